// Round 1
// 225.473 us; speedup vs baseline: 1.0288x; 1.0288x over previous
//
#include <hip/hip_runtime.h>
#include <hip/hip_bf16.h>
#include <math.h>

// Problem constants
#define B 16
#define S 4096
#define D 64
#define NH 8
#define NBUCK 64          // buckets per hash
#define CHUNKS 512        // chunks per batch (NH * NBUCK)
#define BS 64             // bucket/chunk size

#define GAP_MFMA 0.12f    // flag threshold: bf16-R rounding err sigma~0.013 -> 9 sigma

typedef __attribute__((ext_vector_type(8))) short s8_t;   // 8 bf16 (4 VGPRs)
typedef __attribute__((ext_vector_type(4))) float f4_t;   // MFMA C/D

__device__ inline unsigned short bf16_rne(float x) {
    unsigned int u = __float_as_uint(x);
    u += 0x7fffu + ((u >> 16) & 1u);
    return (unsigned short)(u >> 16);
}
__device__ inline unsigned int pack_bf16_pair(float x0, float x1) {
    return (unsigned int)bf16_rne(x0) | ((unsigned int)bf16_rne(x1) << 16);
}
__device__ inline void split_bf16(float x, unsigned short& h, unsigned short& l) {
    h = bf16_rne(x);
    float hf = __uint_as_float(((unsigned int)h) << 16);
    l = bf16_rne(x - hf);
}
// truncation-pack two f32 into (bf16(x0) | bf16(x1)<<16): one v_perm_b32
__device__ inline unsigned int pack_trunc(float x0, float x1) {
    return __builtin_amdgcn_perm(__float_as_uint(x1), __float_as_uint(x0),
                                 0x07060302u);
}
__device__ inline unsigned short bf16_trunc(float x) {
    return (unsigned short)(__float_as_uint(x) >> 16);
}

// ---------------------------------------------------------------------------
// Kernel 1: MFMA hash (GEMM form). A[m=256 outputs (8h x 32i)][k=64] = R bf16,
// B[k=64][n=128 tokens] = qk split hi/lo (2 MFMAs each). Per odd m-tile,
// finalize per-h top-2 of signed candidates [v,-v] via quad butterfly.
// Ambiguous tokens (gap < GAP_MFMA) get flag byte = 1 (no global atomics).
// XCD-contiguous blockIdx swizzle: each XCD works 2 batches' tiles -> qk[b]
// stays L2-resident for the gather-free coalesced staging.
// ---------------------------------------------------------------------------
#define HA_OFF 0          // A (R) : 256 rows x 144 B
#define HQH_OFF 36864     // Q hi  : 128 rows x 144 B
#define HQL_OFF 55296     // Q lo  : 128 rows x 144 B
#define HLDS_TOT 73728
#define HSTR 144          // row stride bytes (64 bf16 + 8 pad)

__global__ __launch_bounds__(256, 2) void hash_kernel(
    const float* __restrict__ qk, const float* __restrict__ rot,
    float* __restrict__ out_buckets, int* __restrict__ bucket_ws,
    unsigned char* __restrict__ flag_ws)
{
    __shared__ char lds[HLDS_TOT];
    int tid = threadIdx.x;
    int wg = blockIdx.x;                       // 512 blocks, 512%8==0
    int orig = ((wg & 7) << 6) + (wg >> 3);    // XCD-contiguous remap
    int b    = orig >> 5;
    int tile = orig & 31;
    int token0 = tile * 128;

    // ---- stage A = R_all: A[m][f] = rot[f*256 + m], bf16 RNE ----
    {
        char* arow = lds + HA_OFF + tid * HSTR;
        #pragma unroll 4
        for (int f = 0; f < 64; f += 2) {
            float r0 = rot[(size_t)f * 256 + tid];
            float r1 = rot[(size_t)(f + 1) * 256 + tid];
            *(unsigned int*)(arow + f * 2) = pack_bf16_pair(r0, r1);
        }
    }
    // ---- stage B = qk tile, split hi/lo ----
    {
        int r = tid >> 1, half = tid & 1;
        int tok = token0 + r;
        const float4* qs = (const float4*)(qk + ((size_t)b * S + tok) * D) + half * 8;
        float xq[32];
        #pragma unroll
        for (int e4 = 0; e4 < 8; ++e4) {
            float4 a = qs[e4];
            xq[e4*4+0]=a.x; xq[e4*4+1]=a.y; xq[e4*4+2]=a.z; xq[e4*4+3]=a.w;
        }
        unsigned int ph[16], pl[16];
        #pragma unroll
        for (int e = 0; e < 16; ++e) {
            unsigned short h0,l0,h1,l1;
            split_bf16(xq[2*e],   h0, l0);
            split_bf16(xq[2*e+1], h1, l1);
            ph[e] = (unsigned int)h0 | ((unsigned int)h1 << 16);
            pl[e] = (unsigned int)l0 | ((unsigned int)l1 << 16);
        }
        char* qh = lds + HQH_OFF + r * HSTR + half * 64;
        char* ql = lds + HQL_OFF + r * HSTR + half * 64;
        #pragma unroll
        for (int e4 = 0; e4 < 4; ++e4) {
            *(uint4*)(qh + e4*16) = make_uint4(ph[e4*4], ph[e4*4+1], ph[e4*4+2], ph[e4*4+3]);
            *(uint4*)(ql + e4*16) = make_uint4(pl[e4*4], pl[e4*4+1], pl[e4*4+2], pl[e4*4+3]);
        }
    }
    __syncthreads();

    int wv   = tid >> 6;
    int lane = tid & 63;
    int quad = lane >> 4;
    int cc   = lane & 15;

    for (int nt = 0; nt < 2; ++nt) {
        int ntg = wv * 2 + nt;            // 0..7 (16-token groups)
        const char* qrh = lds + HQH_OFF + (ntg * 16 + cc) * HSTR + quad * 16;
        const char* qrl = lds + HQL_OFF + (ntg * 16 + cc) * HSTR + quad * 16;
        s8_t bh0 = *(const s8_t*)(qrh);
        s8_t bh1 = *(const s8_t*)(qrh + 64);
        s8_t bl0 = *(const s8_t*)(qrl);
        s8_t bl1 = *(const s8_t*)(qrl + 64);

        float v1 = -3e38f, v2 = -3e38f;
        int i1 = 0;

        for (int mt = 0; mt < 16; ++mt) {
            const char* arow = lds + HA_OFF + (mt * 16 + cc) * HSTR + quad * 16;
            s8_t a0 = *(const s8_t*)(arow);
            s8_t a1 = *(const s8_t*)(arow + 64);
            f4_t acc = (f4_t){0.f, 0.f, 0.f, 0.f};
            acc = __builtin_amdgcn_mfma_f32_16x16x32_bf16(a0, bh0, acc, 0, 0, 0);
            acc = __builtin_amdgcn_mfma_f32_16x16x32_bf16(a1, bh1, acc, 0, 0, 0);
            acc = __builtin_amdgcn_mfma_f32_16x16x32_bf16(a0, bl0, acc, 0, 0, 0);
            acc = __builtin_amdgcn_mfma_f32_16x16x32_bf16(a1, bl1, acc, 0, 0, 0);

            if ((mt & 1) == 0) { v1 = -3e38f; v2 = -3e38f; i1 = 0; }
            int ibase = ((mt & 1) << 4) + (quad << 2);
            #pragma unroll
            for (int r = 0; r < 4; ++r) {
                float vp = acc[r];
                int ip = ibase + r;
                v2 = fmaxf(v2, fminf(vp, v1));
                if (vp > v1) { v1 = vp; i1 = ip; }
                float vn = -vp;
                v2 = fmaxf(v2, fminf(vn, v1));
                if (vn > v1) { v1 = vn; i1 = ip + 32; }
            }

            if (mt & 1) {
                // butterfly merge across the 4 quads (lane bits 4,5)
                #pragma unroll
                for (int off = 16; off <= 32; off <<= 1) {
                    float ov1 = __shfl_xor(v1, off, 64);
                    float ov2 = __shfl_xor(v2, off, 64);
                    int   oi1 = __shfl_xor(i1, off, 64);
                    float nv2 = fmaxf(fmaxf(v2, ov2), fminf(v1, ov1));
                    if (ov1 > v1) { v1 = ov1; i1 = oi1; }
                    v2 = nv2;
                }
                if (quad == 0) {
                    int h = mt >> 1;
                    int tok = token0 + ntg * 16 + cc;
                    size_t idx = (size_t)(b * NH + h) * S + tok;
                    bucket_ws[idx] = i1;
                    out_buckets[idx] = (float)(i1 + h * NBUCK);
                    flag_ws[idx] = (v1 - v2 < GAP_MFMA) ? 1 : 0;  // fire-and-forget
                }
            }
        }
    }
}

// ---------------------------------------------------------------------------
// Kernel 1b: exact f64 recompute for flagged tokens. Block-local compaction
// (LDS counter, zero global atomics) over 2048-token tiles, then the
// compacted list is processed densely (no wave-divergence waste).
// ---------------------------------------------------------------------------
__global__ __launch_bounds__(256) void hash_fixup_kernel(
    const float* __restrict__ qk, const float* __restrict__ rot,
    const unsigned char* __restrict__ flag_ws,
    float* __restrict__ out_buckets, int* __restrict__ bucket_ws)
{
    __shared__ int list[2048];
    __shared__ int cnt;
    int tid = threadIdx.x;
    if (tid == 0) cnt = 0;
    __syncthreads();

    int base = blockIdx.x * 2048;
    for (int i = tid; i < 2048; i += 256) {
        if (flag_ws[base + i]) {
            int slot = atomicAdd(&cnt, 1);    // LDS atomic (block-local)
            list[slot] = base + i;
        }
    }
    __syncthreads();
    int n = cnt;

    for (int j = tid; j < n; j += 256) {
        int gid = list[j];
        int bh = gid >> 12, t = gid & (S - 1);
        int b = bh >> 3, h = bh & 7;
        const float* row = qk + ((size_t)b * S + t) * D;

        double acc[32];
        #pragma unroll
        for (int i = 0; i < 32; ++i) acc[i] = 0.0;
        for (int f = 0; f < 64; ++f) {
            double x = (double)row[f];
            const float* rr = rot + f * (NH * 32) + h * 32;
            #pragma unroll
            for (int i = 0; i < 32; ++i)
                acc[i] = __fma_rn(x, (double)rr[i], acc[i]);
        }
        double best = acc[0]; int bi = 0;
        double worst = acc[0]; int wi = 0;
        #pragma unroll
        for (int i = 1; i < 32; ++i) {
            if (acc[i] > best)  { best = acc[i]; bi = i; }
            if (acc[i] < worst) { worst = acc[i]; wi = i; }
        }
        int bucket = (-worst > best) ? (32 + wi) : bi;
        bucket_ws[gid] = bucket;
        out_buckets[gid] = (float)(bucket + h * NBUCK);
    }
}

// ---------------------------------------------------------------------------
// Kernel 2: parallel stable counting sort per (b,h). 256 threads (4 waves).
// ---------------------------------------------------------------------------
__global__ __launch_bounds__(256) void sort_kernel(
    const int* __restrict__ bucket_ws, int* __restrict__ st_ws)
{
    __shared__ int sb[S];
    __shared__ int hist[4][64];
    __shared__ int bpref[64];
    __shared__ int woff[4][64];

    int tid  = threadIdx.x;
    int wv   = tid >> 6;
    int lane = tid & 63;
    int base = blockIdx.x * S;

    hist[wv][lane] = 0;
    __syncthreads();

    int qbase = wv * 1024;
    #pragma unroll
    for (int i = 0; i < 16; ++i) {
        int t = qbase + i * 64 + lane;
        int v = bucket_ws[base + t];
        sb[t] = v;
        atomicAdd(&hist[wv][v], 1);
    }
    __syncthreads();

    if (wv == 0) {
        int total = hist[0][lane] + hist[1][lane] + hist[2][lane] + hist[3][lane];
        int x = total;
        #pragma unroll
        for (int off = 1; off < 64; off <<= 1) {
            int y = __shfl_up(x, off, 64);
            if (lane >= off) x += y;
        }
        bpref[lane] = x - total;
    }
    __syncthreads();
    {
        int o = bpref[lane];
        for (int w2 = 0; w2 < 4; ++w2) {
            if (w2 < wv) o += hist[w2][lane];
        }
        woff[wv][lane] = o;
    }
    __syncthreads();

    for (int g = 0; g < 16; ++g) {
        int t = qbase + g * 64 + lane;
        int v = sb[t];

        unsigned long long m = ~0ULL;
        #pragma unroll
        for (int bit = 0; bit < 6; ++bit) {
            unsigned long long bm = __ballot((v >> bit) & 1);
            m &= ((v >> bit) & 1) ? bm : ~bm;
        }
        unsigned long long below = (lane == 63) ? ~0ULL >> 1
                                 : ((1ULL << lane) - 1ULL);
        int rank = __popcll(m & below);
        int cnt  = __popcll(m);

        int pos = woff[wv][v] + rank;
        st_ws[base + pos] = t;

        if ((m & below) == 0ULL)
            woff[wv][v] += cnt;
        __builtin_amdgcn_s_waitcnt(0);
    }
}

// ---------------------------------------------------------------------------
// Kernel 3: per-chunk attention, plain-bf16 MFMA, truncation-packed converts.
// LDS layout (36864 B -> 4 blocks/CU):
//   K  [128 rows][144 B] @0      (18432)  normalized keys bf16
//      -- after dots, region overlaid by P[64 rows][272 B stride] (17390 B,
//         256 B data/row: NO row aliasing; 272B = 68 dw = 4*odd -> 2-way max)
//   VtP[64 rows][272 B]  @18432  (17408)  V^T packed: dword = keys(2a,2a+1)
//                                          (68-dw stride: conflict-free b128)
//   nrm @35840 (512), tkx @36352 (512)
// Barriers: 2 (stagers load their own tokens straight from st_ws).
// PV computes O^T (mfma(V^T,P)): lane holds one query's dims in 4 contiguous
// quads -> epilogue is 4 dwordx2 stores/thread instead of 16 scalar b16.
// ---------------------------------------------------------------------------
#define OFF_VT 18432
#define OFF_NRM 35840
#define OFF_TKX 36352
#define LDS_TOT 36864
#define KSTRB 144     // K row stride bytes (72 bf16), 16B-aligned, 36 dw
#define PSTRB 272     // P row stride bytes (136 bf16), 68 dw
#define VSTRD 68      // VtP row stride in dwords (272 B)

__global__ __launch_bounds__(256, 4) void attn_kernel(
    const float* __restrict__ qk, const float* __restrict__ v,
    const int* __restrict__ st_ws,
    __hip_bfloat16* __restrict__ o_ws, float* __restrict__ logits_ws)
{
    __shared__ char lds[LDS_TOT];
    float* nrm_s = (float*)(lds + OFF_NRM);
    int*   tkx   = (int*)(lds + OFF_TKX);
    unsigned int* VtP = (unsigned int*)(lds + OFF_VT);

    int tid = threadIdx.x;
    // XCD-contiguous swizzle: 8192 blocks, each XCD gets 1024 consecutive
    // (b,c) -> resident blocks share one batch's 4MB qk/v working set in L2.
    int wg = blockIdx.x;
    int orig = ((wg & 7) << 10) + (wg >> 3);
    int c = orig & (CHUNKS - 1);
    int b = orig >> 9;
    int h = c >> 6;
    int sbase = b * (NH * S);
    int cprev = (c + CHUNKS - 1) & (CHUNKS - 1);

    // ---- stage K (normalized bf16, row-major); writes tkx/nrm for later ----
    {
        int r = tid >> 1, half = tid & 1;
        int ch = (r < 64) ? c : cprev;
        int tok = st_ws[sbase + ch * BS + (r & 63)];
        if (!half) tkx[r] = tok;
        const float4* qs = (const float4*)(qk + ((size_t)b * S + tok) * D) + half * 8;
        float xq[32];
        #pragma unroll
        for (int e4 = 0; e4 < 8; ++e4) {
            float4 a = qs[e4];
            xq[e4*4+0]=a.x; xq[e4*4+1]=a.y; xq[e4*4+2]=a.z; xq[e4*4+3]=a.w;
        }
        float ss = 0.f;
        #pragma unroll
        for (int e = 0; e < 32; ++e) ss += xq[e]*xq[e];
        ss += __shfl_xor(ss, 1);
        float nr = sqrtf(ss);
        float inv = 1.0f / fmaxf(nr, 1e-12f);
        if (!half) nrm_s[r] = nr;

        unsigned int pk[16];
        #pragma unroll
        for (int e = 0; e < 16; ++e)
            pk[e] = pack_trunc(xq[2*e] * inv, xq[2*e+1] * inv);
        char* kb = lds + r * KSTRB + half * 64;
        #pragma unroll
        for (int e4 = 0; e4 < 4; ++e4)
            *(uint4*)(kb + e4*16) = make_uint4(pk[e4*4], pk[e4*4+1], pk[e4*4+2], pk[e4*4+3]);
    }
    // ---- stage V^T packed (dword = 2 consecutive keys) ----
    {
        int a = tid & 63, sub = tid >> 6;     // a = key pair, sub = dim quarter
        int ch = (a < 32) ? c : cprev;        // keys 2a,2a+1 same chunk (2a even)
        int tok0 = st_ws[sbase + ch * BS + ((2*a)   & 63)];
        int tok1 = st_ws[sbase + ch * BS + ((2*a+1) & 63)];
        const float4* v0 = (const float4*)(v + ((size_t)b * S + tok0) * D + sub * 16);
        const float4* v1 = (const float4*)(v + ((size_t)b * S + tok1) * D + sub * 16);
        float x0[16], x1[16];
        #pragma unroll
        for (int e4 = 0; e4 < 4; ++e4) {
            float4 p0 = v0[e4], p1 = v1[e4];
            x0[e4*4+0]=p0.x; x0[e4*4+1]=p0.y; x0[e4*4+2]=p0.z; x0[e4*4+3]=p0.w;
            x1[e4*4+0]=p1.x; x1[e4*4+1]=p1.y; x1[e4*4+2]=p1.z; x1[e4*4+3]=p1.w;
        }
        #pragma unroll
        for (int e = 0; e < 16; ++e) {
            int dd = sub * 16 + e;
            VtP[dd * VSTRD + a] = pack_trunc(x0[e], x1[e]);
        }
    }
    __syncthreads();

    int wv   = tid >> 6;
    int lane = tid & 63;
    int quad = lane >> 4;
    int cc   = lane & 15;

    // ---- dots: QK^T via bf16 MFMA ----
    int qrow = wv * 16 + cc;
    f4_t acc[8];
    #pragma unroll
    for (int t = 0; t < 8; ++t) acc[t] = (f4_t){0.f,0.f,0.f,0.f};

    __builtin_amdgcn_s_setprio(1);
    #pragma unroll
    for (int kc = 0; kc < 2; ++kc) {
        int aoff = kc * 64 + quad * 16;
        s8_t av = *(const s8_t*)(lds + qrow * KSTRB + aoff);
        #pragma unroll
        for (int t = 0; t < 8; ++t) {
            s8_t bv = *(const s8_t*)(lds + (t * 16 + cc) * KSTRB + aoff);
            acc[t] = __builtin_amdgcn_mfma_f32_16x16x32_bf16(av, bv, acc[t], 0, 0, 0);
        }
    }
    __builtin_amdgcn_s_setprio(0);

    // ---- scale + self-mask + softmax ----
    int tqi[4];
    float sc[4];
    #pragma unroll
    for (int g = 0; g < 4; ++g) {
        int q = wv * 16 + quad * 4 + g;
        tqi[g] = tkx[q];
        sc[g] = nrm_s[q] * 0.125f;
    }
    int tki[8];
    #pragma unroll
    for (int t = 0; t < 8; ++t) tki[t] = tkx[t * 16 + cc];

    #pragma unroll
    for (int t = 0; t < 8; ++t)
        #pragma unroll
        for (int g = 0; g < 4; ++g) {
            float d = acc[t][g] * sc[g];
            if (tqi[g] == tki[t]) d = -1e5f;
            acc[t][g] = d;
        }

    float mx[4];
    #pragma unroll
    for (int g = 0; g < 4; ++g) {
        float m = acc[0][g];
        #pragma unroll
        for (int t = 1; t < 8; ++t) m = fmaxf(m, acc[t][g]);
        mx[g] = m;
    }
    #pragma unroll
    for (int msk = 1; msk <= 8; msk <<= 1)
        #pragma unroll
        for (int g = 0; g < 4; ++g) mx[g] = fmaxf(mx[g], __shfl_xor(mx[g], msk, 64));

    float sm[4] = {0.f, 0.f, 0.f, 0.f};
    #pragma unroll
    for (int t = 0; t < 8; ++t)
        #pragma unroll
        for (int g = 0; g < 4; ++g) {
            float p = __expf(acc[t][g] - mx[g]);
            acc[t][g] = p;
            sm[g] += p;
        }
    #pragma unroll
    for (int msk = 1; msk <= 8; msk <<= 1)
        #pragma unroll
        for (int g = 0; g < 4; ++g) sm[g] += __shfl_xor(sm[g], msk, 64);

    float pinv[4];
    #pragma unroll
    for (int g = 0; g < 4; ++g) pinv[g] = 1.0f / sm[g];

    if (cc == 0) {
        #pragma unroll
        for (int g = 0; g < 4; ++g)
            logits_ws[sbase + h * S + tqi[g]] = mx[g] + __logf(sm[g]);
    }

    // ---- P -> bf16 into LDS (stride PSTRB: no row aliasing), overlaying K --
    __syncthreads();
    #pragma unroll
    for (int t = 0; t < 8; ++t) {
        int key = t * 16 + cc;
        #pragma unroll
        for (int g = 0; g < 4; ++g) {
            int q = wv * 16 + quad * 4 + g;
            *(unsigned short*)(lds + q * PSTRB + key * 2) =
                bf16_trunc(acc[t][g] * pinv[g]);
        }
    }

    // ---- PV as O^T = V^T * P : A = VtP rows (dims), B = own wave's P rows.
    // D[m=dim-in-tile][n=query]: lane holds query (wv*16+cc), dims
    // n*16+quad*4+{0..3} -> contiguous epilogue stores, no shuffles.
    f4_t oaccT[4];
    #pragma unroll
    for (int n = 0; n < 4; ++n) oaccT[n] = (f4_t){0.f,0.f,0.f,0.f};

    __builtin_amdgcn_s_setprio(1);
    #pragma unroll
    for (int kc = 0; kc < 4; ++kc) {
        int koff = kc * 64 + quad * 16;   // byte offset: key k at byte 2k
        s8_t pb = *(const s8_t*)(lds + (wv * 16 + cc) * PSTRB + koff);
        #pragma unroll
        for (int n = 0; n < 4; ++n) {
            s8_t va = *(const s8_t*)((const char*)(VtP + (n * 16 + cc) * VSTRD) + koff);
            oaccT[n] = __builtin_amdgcn_mfma_f32_16x16x32_bf16(va, pb, oaccT[n], 0, 0, 0);
        }
    }
    __builtin_amdgcn_s_setprio(0);

    // ---- write O (bf16 trunc): 4 x 8B stores per thread, one query/lane ----
    {
        int q = wv * 16 + cc;
        int tok = tkx[q];                 // tkx region not overlaid by P
        __hip_bfloat16* op = o_ws + ((size_t)(sbase + h * S + tok)) * D + quad * 4;
        #pragma unroll
        for (int n = 0; n < 4; ++n) {
            uint2 pk2;
            pk2.x = pack_trunc(oaccT[n][0], oaccT[n][1]);
            pk2.y = pack_trunc(oaccT[n][2], oaccT[n][3]);
            *(uint2*)(op + n * 16) = pk2;
        }
    }
}

// ---------------------------------------------------------------------------
// Kernel 4: combine hash rounds with softmax(logits) weights. o_ws is bf16.
// ---------------------------------------------------------------------------
__global__ __launch_bounds__(256) void combine_kernel(
    const __hip_bfloat16* __restrict__ o_ws, const float* __restrict__ logits_ws,
    float* __restrict__ out)
{
    int gid = blockIdx.x * 256 + threadIdx.x;
    int token = gid >> 3;          // b*S + t
    int d8 = gid & 7;
    int b = token >> 12;
    int t = token & (S - 1);
    int base = b * (NH * S) + t;

    float l[8];
    #pragma unroll
    for (int hh = 0; hh < 8; ++hh) l[hh] = logits_ws[base + hh * S];
    float m = l[0];
    #pragma unroll
    for (int hh = 1; hh < 8; ++hh) m = fmaxf(m, l[hh]);
    float w[8]; float ssum = 0.f;
    #pragma unroll
    for (int hh = 0; hh < 8; ++hh) { w[hh] = __expf(l[hh] - m); ssum += w[hh]; }
    float inv = 1.0f / ssum;

    float accv[8] = {0,0,0,0,0,0,0,0};
    #pragma unroll
    for (int hh = 0; hh < 8; ++hh) {
        uint4 pk = *(const uint4*)(o_ws + (size_t)(base + hh * S) * D + d8 * 8);
        float wh = w[hh] * inv;
        unsigned int ws_[4] = {pk.x, pk.y, pk.z, pk.w};
        #pragma unroll
        for (int e = 0; e < 4; ++e) {
            float lo = __uint_as_float(ws_[e] << 16);
            float hi = __uint_as_float(ws_[e] & 0xffff0000u);
            accv[2*e]   += wh * lo;
            accv[2*e+1] += wh * hi;
        }
    }
    float4* op = (float4*)(out + (size_t)token * D + d8 * 8);
    op[0] = make_float4(accv[0], accv[1], accv[2], accv[3]);
    op[1] = make_float4(accv[4], accv[5], accv[6], accv[7]);
}

// ---------------------------------------------------------------------------
extern "C" void kernel_launch(void* const* d_in, const int* in_sizes, int n_in,
                              void* d_out, int out_size, void* d_ws, size_t ws_size,
                              hipStream_t stream) {
    const float* qk  = (const float*)d_in[0];
    const float* v   = (const float*)d_in[1];
    const float* rot = (const float*)d_in[2];

    float* out         = (float*)d_out;
    float* out_buckets = out + (size_t)B * S * D;

    int*   bucket_ws = (int*)d_ws;                              // 524288 ints
    int*   st_ws     = bucket_ws + (size_t)B * NH * S;          // 524288 ints
    float* logits_ws = (float*)(st_ws + (size_t)B * NH * S);    // 524288 f32
    __hip_bfloat16* o_ws = (__hip_bfloat16*)(logits_ws + (size_t)B * NH * S); // 64 MB
    unsigned char* flag_ws = (unsigned char*)(o_ws + (size_t)B * NH * S * D); // 512 KB

    hash_kernel<<<B * 32, 256, 0, stream>>>(qk, rot, out_buckets, bucket_ws,
                                            flag_ws);
    hash_fixup_kernel<<<(B * NH * S) / 2048, 256, 0, stream>>>(
        qk, rot, flag_ws, out_buckets, bucket_ws);
    sort_kernel<<<B * NH, 256, 0, stream>>>(bucket_ws, st_ws);
    attn_kernel<<<B * CHUNKS, 256, 0, stream>>>(qk, v, st_ws, o_ws, logits_ws);
    combine_kernel<<<(B * S * 8) / 256, 256, 0, stream>>>(o_ws, logits_ws, out);
}

// Round 2
// 223.205 us; speedup vs baseline: 1.0392x; 1.0102x over previous
//
#include <hip/hip_runtime.h>
#include <hip/hip_bf16.h>
#include <math.h>

// Problem constants
#define B 16
#define S 4096
#define D 64
#define NH 8
#define NBUCK 64          // buckets per hash
#define CHUNKS 512        // chunks per batch (NH * NBUCK)
#define BS 64             // bucket/chunk size

#define GAP_MFMA 0.12f    // flag threshold: bf16-R rounding err sigma~0.013 -> 9 sigma

typedef __attribute__((ext_vector_type(8))) short s8_t;   // 8 bf16 (4 VGPRs)
typedef __attribute__((ext_vector_type(4))) float f4_t;   // MFMA C/D

__device__ inline unsigned short bf16_rne(float x) {
    unsigned int u = __float_as_uint(x);
    u += 0x7fffu + ((u >> 16) & 1u);
    return (unsigned short)(u >> 16);
}
__device__ inline unsigned int pack_bf16_pair(float x0, float x1) {
    return (unsigned int)bf16_rne(x0) | ((unsigned int)bf16_rne(x1) << 16);
}
__device__ inline void split_bf16(float x, unsigned short& h, unsigned short& l) {
    h = bf16_rne(x);
    float hf = __uint_as_float(((unsigned int)h) << 16);
    l = bf16_rne(x - hf);
}
// truncation-pack two f32 into (bf16(x0) | bf16(x1)<<16): one v_perm_b32
__device__ inline unsigned int pack_trunc(float x0, float x1) {
    return __builtin_amdgcn_perm(__float_as_uint(x1), __float_as_uint(x0),
                                 0x07060302u);
}
__device__ inline unsigned short bf16_trunc(float x) {
    return (unsigned short)(__float_as_uint(x) >> 16);
}

// lgkm-only barrier: drains LDS writes (required for cross-wave visibility)
// but leaves register-destined global loads and fire-and-forget stores in
// flight (hipcc's __syncthreads emits a full vmcnt(0) drain -- a pure stall
// here since no cross-thread global data is exchanged inside the kernel).
#define BAR_LGKM() do {                                          \
    asm volatile("s_waitcnt lgkmcnt(0)" ::: "memory");           \
    __builtin_amdgcn_s_barrier();                                \
    asm volatile("" ::: "memory");                               \
} while (0)

// ---------------------------------------------------------------------------
// Kernel 1: MFMA hash (GEMM form). A[m=256 outputs (8h x 32i)][k=64] = R bf16,
// B[k=64][n=128 tokens] = qk split hi/lo (2 MFMAs each). Per odd m-tile,
// finalize per-h top-2 of signed candidates [v,-v] via quad butterfly.
// Ambiguous tokens (gap < GAP_MFMA) get flag byte = 1 (no global atomics).
// XCD-contiguous blockIdx swizzle: each XCD works 2 batches' tiles -> qk[b]
// stays L2-resident for the gather-free coalesced staging.
// ---------------------------------------------------------------------------
#define HA_OFF 0          // A (R) : 256 rows x 144 B
#define HQH_OFF 36864     // Q hi  : 128 rows x 144 B
#define HQL_OFF 55296     // Q lo  : 128 rows x 144 B
#define HLDS_TOT 73728
#define HSTR 144          // row stride bytes (64 bf16 + 8 pad)

__global__ __launch_bounds__(256, 2) void hash_kernel(
    const float* __restrict__ qk, const float* __restrict__ rot,
    float* __restrict__ out_buckets, int* __restrict__ bucket_ws,
    unsigned char* __restrict__ flag_ws)
{
    __shared__ char lds[HLDS_TOT];
    int tid = threadIdx.x;
    int wg = blockIdx.x;                       // 512 blocks, 512%8==0
    int orig = ((wg & 7) << 6) + (wg >> 3);    // XCD-contiguous remap
    int b    = orig >> 5;
    int tile = orig & 31;
    int token0 = tile * 128;

    // ---- stage A = R_all: A[m][f] = rot[f*256 + m], bf16 RNE ----
    {
        char* arow = lds + HA_OFF + tid * HSTR;
        #pragma unroll 4
        for (int f = 0; f < 64; f += 2) {
            float r0 = rot[(size_t)f * 256 + tid];
            float r1 = rot[(size_t)(f + 1) * 256 + tid];
            *(unsigned int*)(arow + f * 2) = pack_bf16_pair(r0, r1);
        }
    }
    // ---- stage B = qk tile, split hi/lo ----
    {
        int r = tid >> 1, half = tid & 1;
        int tok = token0 + r;
        const float4* qs = (const float4*)(qk + ((size_t)b * S + tok) * D) + half * 8;
        float xq[32];
        #pragma unroll
        for (int e4 = 0; e4 < 8; ++e4) {
            float4 a = qs[e4];
            xq[e4*4+0]=a.x; xq[e4*4+1]=a.y; xq[e4*4+2]=a.z; xq[e4*4+3]=a.w;
        }
        unsigned int ph[16], pl[16];
        #pragma unroll
        for (int e = 0; e < 16; ++e) {
            unsigned short h0,l0,h1,l1;
            split_bf16(xq[2*e],   h0, l0);
            split_bf16(xq[2*e+1], h1, l1);
            ph[e] = (unsigned int)h0 | ((unsigned int)h1 << 16);
            pl[e] = (unsigned int)l0 | ((unsigned int)l1 << 16);
        }
        char* qh = lds + HQH_OFF + r * HSTR + half * 64;
        char* ql = lds + HQL_OFF + r * HSTR + half * 64;
        #pragma unroll
        for (int e4 = 0; e4 < 4; ++e4) {
            *(uint4*)(qh + e4*16) = make_uint4(ph[e4*4], ph[e4*4+1], ph[e4*4+2], ph[e4*4+3]);
            *(uint4*)(ql + e4*16) = make_uint4(pl[e4*4], pl[e4*4+1], pl[e4*4+2], pl[e4*4+3]);
        }
    }
    __syncthreads();

    int wv   = tid >> 6;
    int lane = tid & 63;
    int quad = lane >> 4;
    int cc   = lane & 15;

    for (int nt = 0; nt < 2; ++nt) {
        int ntg = wv * 2 + nt;            // 0..7 (16-token groups)
        const char* qrh = lds + HQH_OFF + (ntg * 16 + cc) * HSTR + quad * 16;
        const char* qrl = lds + HQL_OFF + (ntg * 16 + cc) * HSTR + quad * 16;
        s8_t bh0 = *(const s8_t*)(qrh);
        s8_t bh1 = *(const s8_t*)(qrh + 64);
        s8_t bl0 = *(const s8_t*)(qrl);
        s8_t bl1 = *(const s8_t*)(qrl + 64);

        float v1 = -3e38f, v2 = -3e38f;
        int i1 = 0;

        for (int mt = 0; mt < 16; ++mt) {
            const char* arow = lds + HA_OFF + (mt * 16 + cc) * HSTR + quad * 16;
            s8_t a0 = *(const s8_t*)(arow);
            s8_t a1 = *(const s8_t*)(arow + 64);
            f4_t acc = (f4_t){0.f, 0.f, 0.f, 0.f};
            acc = __builtin_amdgcn_mfma_f32_16x16x32_bf16(a0, bh0, acc, 0, 0, 0);
            acc = __builtin_amdgcn_mfma_f32_16x16x32_bf16(a1, bh1, acc, 0, 0, 0);
            acc = __builtin_amdgcn_mfma_f32_16x16x32_bf16(a0, bl0, acc, 0, 0, 0);
            acc = __builtin_amdgcn_mfma_f32_16x16x32_bf16(a1, bl1, acc, 0, 0, 0);

            if ((mt & 1) == 0) { v1 = -3e38f; v2 = -3e38f; i1 = 0; }
            int ibase = ((mt & 1) << 4) + (quad << 2);
            #pragma unroll
            for (int r = 0; r < 4; ++r) {
                float vp = acc[r];
                int ip = ibase + r;
                v2 = fmaxf(v2, fminf(vp, v1));
                if (vp > v1) { v1 = vp; i1 = ip; }
                float vn = -vp;
                v2 = fmaxf(v2, fminf(vn, v1));
                if (vn > v1) { v1 = vn; i1 = ip + 32; }
            }

            if (mt & 1) {
                // butterfly merge across the 4 quads (lane bits 4,5)
                #pragma unroll
                for (int off = 16; off <= 32; off <<= 1) {
                    float ov1 = __shfl_xor(v1, off, 64);
                    float ov2 = __shfl_xor(v2, off, 64);
                    int   oi1 = __shfl_xor(i1, off, 64);
                    float nv2 = fmaxf(fmaxf(v2, ov2), fminf(v1, ov1));
                    if (ov1 > v1) { v1 = ov1; i1 = oi1; }
                    v2 = nv2;
                }
                if (quad == 0) {
                    int h = mt >> 1;
                    int tok = token0 + ntg * 16 + cc;
                    size_t idx = (size_t)(b * NH + h) * S + tok;
                    bucket_ws[idx] = i1;
                    out_buckets[idx] = (float)(i1 + h * NBUCK);
                    flag_ws[idx] = (v1 - v2 < GAP_MFMA) ? 1 : 0;  // fire-and-forget
                }
            }
        }
    }
}

// ---------------------------------------------------------------------------
// Kernel 1b: exact f64 recompute for flagged tokens. Block-local compaction
// (LDS counter, zero global atomics) over 2048-token tiles, then the
// compacted list is processed densely (no wave-divergence waste).
// ---------------------------------------------------------------------------
__global__ __launch_bounds__(256) void hash_fixup_kernel(
    const float* __restrict__ qk, const float* __restrict__ rot,
    const unsigned char* __restrict__ flag_ws,
    float* __restrict__ out_buckets, int* __restrict__ bucket_ws)
{
    __shared__ int list[2048];
    __shared__ int cnt;
    int tid = threadIdx.x;
    if (tid == 0) cnt = 0;
    __syncthreads();

    int base = blockIdx.x * 2048;
    for (int i = tid; i < 2048; i += 256) {
        if (flag_ws[base + i]) {
            int slot = atomicAdd(&cnt, 1);    // LDS atomic (block-local)
            list[slot] = base + i;
        }
    }
    __syncthreads();
    int n = cnt;

    for (int j = tid; j < n; j += 256) {
        int gid = list[j];
        int bh = gid >> 12, t = gid & (S - 1);
        int b = bh >> 3, h = bh & 7;
        const float* row = qk + ((size_t)b * S + t) * D;

        double acc[32];
        #pragma unroll
        for (int i = 0; i < 32; ++i) acc[i] = 0.0;
        for (int f = 0; f < 64; ++f) {
            double x = (double)row[f];
            const float* rr = rot + f * (NH * 32) + h * 32;
            #pragma unroll
            for (int i = 0; i < 32; ++i)
                acc[i] = __fma_rn(x, (double)rr[i], acc[i]);
        }
        double best = acc[0]; int bi = 0;
        double worst = acc[0]; int wi = 0;
        #pragma unroll
        for (int i = 1; i < 32; ++i) {
            if (acc[i] > best)  { best = acc[i]; bi = i; }
            if (acc[i] < worst) { worst = acc[i]; wi = i; }
        }
        int bucket = (-worst > best) ? (32 + wi) : bi;
        bucket_ws[gid] = bucket;
        out_buckets[gid] = (float)(bucket + h * NBUCK);
    }
}

// ---------------------------------------------------------------------------
// Kernel 2: parallel stable counting sort per (b,h). 256 threads (4 waves).
// ---------------------------------------------------------------------------
__global__ __launch_bounds__(256) void sort_kernel(
    const int* __restrict__ bucket_ws, int* __restrict__ st_ws)
{
    __shared__ int sb[S];
    __shared__ int hist[4][64];
    __shared__ int bpref[64];
    __shared__ int woff[4][64];

    int tid  = threadIdx.x;
    int wv   = tid >> 6;
    int lane = tid & 63;
    int base = blockIdx.x * S;

    hist[wv][lane] = 0;
    __syncthreads();

    int qbase = wv * 1024;
    #pragma unroll
    for (int i = 0; i < 16; ++i) {
        int t = qbase + i * 64 + lane;
        int v = bucket_ws[base + t];
        sb[t] = v;
        atomicAdd(&hist[wv][v], 1);
    }
    __syncthreads();

    if (wv == 0) {
        int total = hist[0][lane] + hist[1][lane] + hist[2][lane] + hist[3][lane];
        int x = total;
        #pragma unroll
        for (int off = 1; off < 64; off <<= 1) {
            int y = __shfl_up(x, off, 64);
            if (lane >= off) x += y;
        }
        bpref[lane] = x - total;
    }
    __syncthreads();
    {
        int o = bpref[lane];
        for (int w2 = 0; w2 < 4; ++w2) {
            if (w2 < wv) o += hist[w2][lane];
        }
        woff[wv][lane] = o;
    }
    __syncthreads();

    for (int g = 0; g < 16; ++g) {
        int t = qbase + g * 64 + lane;
        int v = sb[t];

        unsigned long long m = ~0ULL;
        #pragma unroll
        for (int bit = 0; bit < 6; ++bit) {
            unsigned long long bm = __ballot((v >> bit) & 1);
            m &= ((v >> bit) & 1) ? bm : ~bm;
        }
        unsigned long long below = (lane == 63) ? ~0ULL >> 1
                                 : ((1ULL << lane) - 1ULL);
        int rank = __popcll(m & below);
        int cnt  = __popcll(m);

        int pos = woff[wv][v] + rank;
        st_ws[base + pos] = t;

        if ((m & below) == 0ULL)
            woff[wv][v] += cnt;
        __builtin_amdgcn_s_waitcnt(0);
    }
}

// ---------------------------------------------------------------------------
// Kernel 3: per-chunk attention, plain-bf16 MFMA, truncation-packed converts.
// LDS layout (36864 B -> 4 blocks/CU):
//   K  [128 rows][144 B] @0      (18432)  normalized keys bf16
//      -- after dots, region overlaid by P[64 rows][272 B stride]
//         (UNNORMALIZED probs; 1/sum deferred to epilogue via nrm_s reuse)
//   VtP[64 rows][272 B]  @18432  (17408)  V^T packed: dword = keys(2a,2a+1)
//   nrm @35840 (512)  -- K norms; rows wv*16..+15 recycled as pinv post-softmax
//   tkx @36352 (512)
// Barriers: 2 raw lgkm-only barriers (global loads/stores stay in flight).
// V gather loads issue in phase A (registers); VtP pack+write happens AFTER
// the QK MFMA loop so V's HBM/L2 latency hides under barrier skew + QK.
// Softmax runs in log2 domain (scale folds log2(e); v_exp_f32 is native 2^x).
// PV computes O^T (mfma(V^T,P)): epilogue is 4 dwordx2 stores/thread.
// ---------------------------------------------------------------------------
#define OFF_VT 18432
#define OFF_NRM 35840
#define OFF_TKX 36352
#define LDS_TOT 36864
#define KSTRB 144     // K row stride bytes (72 bf16), 16B-aligned, 36 dw
#define PSTRB 272     // P row stride bytes (136 bf16), 68 dw
#define VSTRD 68      // VtP row stride in dwords (272 B)

__global__ __launch_bounds__(256, 4) void attn_kernel(
    const float* __restrict__ qk, const float* __restrict__ v,
    const int* __restrict__ st_ws,
    __hip_bfloat16* __restrict__ o_ws, float* __restrict__ logits_ws)
{
    __shared__ char lds[LDS_TOT];
    float* nrm_s = (float*)(lds + OFF_NRM);
    int*   tkx   = (int*)(lds + OFF_TKX);
    unsigned int* VtP = (unsigned int*)(lds + OFF_VT);

    int tid = threadIdx.x;
    // XCD-contiguous swizzle: 8192 blocks, each XCD gets 1024 consecutive
    // (b,c) -> resident blocks share one batch's 4MB qk/v working set in L2.
    int wg = blockIdx.x;
    int orig = ((wg & 7) << 10) + (wg >> 3);
    int c = orig & (CHUNKS - 1);
    int b = orig >> 9;
    int h = c >> 6;
    int sbase = b * (NH * S);
    int cprev = (c + CHUNKS - 1) & (CHUNKS - 1);

    // ---- issue V gather loads early; consumed after the QK MFMA loop ----
    int av_ = tid & 63, sub_ = tid >> 6;      // av_ = key pair, sub_ = dim quarter
    int chv = (av_ < 32) ? c : cprev;         // keys 2a,2a+1 same chunk
    int tokv0 = st_ws[sbase + chv * BS + ((2 * av_)     & 63)];
    int tokv1 = st_ws[sbase + chv * BS + ((2 * av_ + 1) & 63)];
    const float4* vp0 = (const float4*)(v + ((size_t)b * S + tokv0) * D + sub_ * 16);
    const float4* vp1 = (const float4*)(v + ((size_t)b * S + tokv1) * D + sub_ * 16);
    float4 vr0[4], vr1[4];
    #pragma unroll
    for (int e4 = 0; e4 < 4; ++e4) { vr0[e4] = vp0[e4]; vr1[e4] = vp1[e4]; }

    // ---- stage K (normalized bf16, row-major); writes tkx/nrm for later ----
    {
        int r = tid >> 1, half = tid & 1;
        int ch = (r < 64) ? c : cprev;
        int tok = st_ws[sbase + ch * BS + (r & 63)];
        if (!half) tkx[r] = tok;
        const float4* qs = (const float4*)(qk + ((size_t)b * S + tok) * D) + half * 8;
        float xq[32];
        #pragma unroll
        for (int e4 = 0; e4 < 8; ++e4) {
            float4 a = qs[e4];
            xq[e4*4+0]=a.x; xq[e4*4+1]=a.y; xq[e4*4+2]=a.z; xq[e4*4+3]=a.w;
        }
        float ss = 0.f;
        #pragma unroll
        for (int e = 0; e < 32; ++e) ss += xq[e]*xq[e];
        ss += __shfl_xor(ss, 1);
        float nr = sqrtf(ss);
        float inv = 1.0f / fmaxf(nr, 1e-12f);
        if (!half) nrm_s[r] = nr;

        unsigned int pk[16];
        #pragma unroll
        for (int e = 0; e < 16; ++e)
            pk[e] = pack_trunc(xq[2*e] * inv, xq[2*e+1] * inv);
        char* kb = lds + r * KSTRB + half * 64;
        #pragma unroll
        for (int e4 = 0; e4 < 4; ++e4)
            *(uint4*)(kb + e4*16) = make_uint4(pk[e4*4], pk[e4*4+1], pk[e4*4+2], pk[e4*4+3]);
    }
    BAR_LGKM();   // K/tkx/nrm visible; V loads legally still in flight

    int wv   = tid >> 6;
    int lane = tid & 63;
    int quad = lane >> 4;
    int cc   = lane & 15;

    // ---- dots: QK^T via bf16 MFMA ----
    int qrow = wv * 16 + cc;
    f4_t acc[8];
    #pragma unroll
    for (int t = 0; t < 8; ++t) acc[t] = (f4_t){0.f,0.f,0.f,0.f};

    __builtin_amdgcn_s_setprio(1);
    #pragma unroll
    for (int kc = 0; kc < 2; ++kc) {
        int aoff = kc * 64 + quad * 16;
        s8_t av = *(const s8_t*)(lds + qrow * KSTRB + aoff);
        #pragma unroll
        for (int t = 0; t < 8; ++t) {
            s8_t bv = *(const s8_t*)(lds + (t * 16 + cc) * KSTRB + aoff);
            acc[t] = __builtin_amdgcn_mfma_f32_16x16x32_bf16(av, bv, acc[t], 0, 0, 0);
        }
    }
    __builtin_amdgcn_s_setprio(0);

    // ---- pack + write V^T (V loads have arrived under the QK phase) ----
    {
        float x0[16], x1[16];
        #pragma unroll
        for (int e4 = 0; e4 < 4; ++e4) {
            float4 p0 = vr0[e4], p1 = vr1[e4];
            x0[e4*4+0]=p0.x; x0[e4*4+1]=p0.y; x0[e4*4+2]=p0.z; x0[e4*4+3]=p0.w;
            x1[e4*4+0]=p1.x; x1[e4*4+1]=p1.y; x1[e4*4+2]=p1.z; x1[e4*4+3]=p1.w;
        }
        #pragma unroll
        for (int e = 0; e < 16; ++e) {
            int dd = sub_ * 16 + e;
            VtP[dd * VSTRD + av_] = pack_trunc(x0[e], x1[e]);
        }
    }

    // ---- scale + self-mask + softmax (log2 domain) ----
    int tqi[4];
    float sc[4];
    #pragma unroll
    for (int g = 0; g < 4; ++g) {
        int q = wv * 16 + quad * 4 + g;
        tqi[g] = tkx[q];
        sc[g] = nrm_s[q] * 0.18033688f;     // 0.125 * log2(e)
    }
    int tki[8];
    #pragma unroll
    for (int t = 0; t < 8; ++t) tki[t] = tkx[t * 16 + cc];

    #pragma unroll
    for (int t = 0; t < 8; ++t)
        #pragma unroll
        for (int g = 0; g < 4; ++g) {
            float d = acc[t][g] * sc[g];
            if (tqi[g] == tki[t]) d = -3e5f;   // log2-domain mask
            acc[t][g] = d;
        }

    float mx[4];
    #pragma unroll
    for (int g = 0; g < 4; ++g) {
        float m = acc[0][g];
        #pragma unroll
        for (int t = 1; t < 8; ++t) m = fmaxf(m, acc[t][g]);
        mx[g] = m;
    }
    #pragma unroll
    for (int msk = 1; msk <= 8; msk <<= 1)
        #pragma unroll
        for (int g = 0; g < 4; ++g) mx[g] = fmaxf(mx[g], __shfl_xor(mx[g], msk, 64));

    float sm[4] = {0.f, 0.f, 0.f, 0.f};
    #pragma unroll
    for (int t = 0; t < 8; ++t)
        #pragma unroll
        for (int g = 0; g < 4; ++g) {
            float p = __builtin_amdgcn_exp2f(acc[t][g] - mx[g]);
            acc[t][g] = p;
            sm[g] += p;
        }
    #pragma unroll
    for (int msk = 1; msk <= 8; msk <<= 1)
        #pragma unroll
        for (int g = 0; g < 4; ++g) sm[g] += __shfl_xor(sm[g], msk, 64);

    if (cc == 0) {
        #pragma unroll
        for (int g = 0; g < 4; ++g) {
            int q = wv * 16 + quad * 4 + g;
            nrm_s[q] = 1.0f / sm[g];        // recycle nrm slot as pinv (own wave)
            logits_ws[sbase + h * S + tqi[g]] =
                0.69314718f * (mx[g] + __log2f(sm[g]));
        }
    }

    // ---- P -> bf16 into LDS (UNNORMALIZED; stride PSTRB), overlaying K ----
    BAR_LGKM();   // all QK reads of K done; logits store stays in flight
    #pragma unroll
    for (int t = 0; t < 8; ++t) {
        int key = t * 16 + cc;
        #pragma unroll
        for (int g = 0; g < 4; ++g) {
            int q = wv * 16 + quad * 4 + g;
            *(unsigned short*)(lds + q * PSTRB + key * 2) =
                bf16_trunc(acc[t][g]);
        }
    }

    // ---- PV as O^T = V^T * P : A = VtP rows (dims), B = own wave's P rows.
    f4_t oaccT[4];
    #pragma unroll
    for (int n = 0; n < 4; ++n) oaccT[n] = (f4_t){0.f,0.f,0.f,0.f};

    __builtin_amdgcn_s_setprio(1);
    #pragma unroll
    for (int kc = 0; kc < 4; ++kc) {
        int koff = kc * 64 + quad * 16;   // byte offset: key k at byte 2k
        s8_t pb = *(const s8_t*)(lds + (wv * 16 + cc) * PSTRB + koff);
        #pragma unroll
        for (int n = 0; n < 4; ++n) {
            s8_t va = *(const s8_t*)((const char*)(VtP + (n * 16 + cc) * VSTRD) + koff);
            oaccT[n] = __builtin_amdgcn_mfma_f32_16x16x32_bf16(va, pb, oaccT[n], 0, 0, 0);
        }
    }
    __builtin_amdgcn_s_setprio(0);

    // ---- write O (bf16 trunc, scaled by deferred pinv): 4 x 8B stores ----
    {
        int q = wv * 16 + cc;
        int tok = tkx[q];                 // tkx region not overlaid by P
        float pq = nrm_s[q];              // pinv (written by own wave)
        __hip_bfloat16* op = o_ws + ((size_t)(sbase + h * S + tok)) * D + quad * 4;
        #pragma unroll
        for (int n = 0; n < 4; ++n) {
            uint2 pk2;
            pk2.x = pack_trunc(oaccT[n][0] * pq, oaccT[n][1] * pq);
            pk2.y = pack_trunc(oaccT[n][2] * pq, oaccT[n][3] * pq);
            *(uint2*)(op + n * 16) = pk2;
        }
    }
}

// ---------------------------------------------------------------------------
// Kernel 4: combine hash rounds with softmax(logits) weights. o_ws is bf16.
// ---------------------------------------------------------------------------
__global__ __launch_bounds__(256) void combine_kernel(
    const __hip_bfloat16* __restrict__ o_ws, const float* __restrict__ logits_ws,
    float* __restrict__ out)
{
    int gid = blockIdx.x * 256 + threadIdx.x;
    int token = gid >> 3;          // b*S + t
    int d8 = gid & 7;
    int b = token >> 12;
    int t = token & (S - 1);
    int base = b * (NH * S) + t;

    float l[8];
    #pragma unroll
    for (int hh = 0; hh < 8; ++hh) l[hh] = logits_ws[base + hh * S];
    float m = l[0];
    #pragma unroll
    for (int hh = 1; hh < 8; ++hh) m = fmaxf(m, l[hh]);
    float w[8]; float ssum = 0.f;
    #pragma unroll
    for (int hh = 0; hh < 8; ++hh) { w[hh] = __expf(l[hh] - m); ssum += w[hh]; }
    float inv = 1.0f / ssum;

    float accv[8] = {0,0,0,0,0,0,0,0};
    #pragma unroll
    for (int hh = 0; hh < 8; ++hh) {
        uint4 pk = *(const uint4*)(o_ws + (size_t)(base + hh * S) * D + d8 * 8);
        float wh = w[hh] * inv;
        unsigned int ws_[4] = {pk.x, pk.y, pk.z, pk.w};
        #pragma unroll
        for (int e = 0; e < 4; ++e) {
            float lo = __uint_as_float(ws_[e] << 16);
            float hi = __uint_as_float(ws_[e] & 0xffff0000u);
            accv[2*e]   += wh * lo;
            accv[2*e+1] += wh * hi;
        }
    }
    float4* op = (float4*)(out + (size_t)token * D + d8 * 8);
    op[0] = make_float4(accv[0], accv[1], accv[2], accv[3]);
    op[1] = make_float4(accv[4], accv[5], accv[6], accv[7]);
}

// ---------------------------------------------------------------------------
extern "C" void kernel_launch(void* const* d_in, const int* in_sizes, int n_in,
                              void* d_out, int out_size, void* d_ws, size_t ws_size,
                              hipStream_t stream) {
    const float* qk  = (const float*)d_in[0];
    const float* v   = (const float*)d_in[1];
    const float* rot = (const float*)d_in[2];

    float* out         = (float*)d_out;
    float* out_buckets = out + (size_t)B * S * D;

    int*   bucket_ws = (int*)d_ws;                              // 524288 ints
    int*   st_ws     = bucket_ws + (size_t)B * NH * S;          // 524288 ints
    float* logits_ws = (float*)(st_ws + (size_t)B * NH * S);    // 524288 f32
    __hip_bfloat16* o_ws = (__hip_bfloat16*)(logits_ws + (size_t)B * NH * S); // 64 MB
    unsigned char* flag_ws = (unsigned char*)(o_ws + (size_t)B * NH * S * D); // 512 KB

    hash_kernel<<<B * 32, 256, 0, stream>>>(qk, rot, out_buckets, bucket_ws,
                                            flag_ws);
    hash_fixup_kernel<<<(B * NH * S) / 2048, 256, 0, stream>>>(
        qk, rot, flag_ws, out_buckets, bucket_ws);
    sort_kernel<<<B * NH, 256, 0, stream>>>(bucket_ws, st_ws);
    attn_kernel<<<B * CHUNKS, 256, 0, stream>>>(qk, v, st_ws, o_ws, logits_ws);
    combine_kernel<<<(B * S * 8) / 256, 256, 0, stream>>>(o_ws, logits_ws, out);
}

// Round 3
// 220.216 us; speedup vs baseline: 1.0533x; 1.0136x over previous
//
#include <hip/hip_runtime.h>
#include <hip/hip_bf16.h>
#include <math.h>

// Problem constants
#define B 16
#define S 4096
#define D 64
#define NH 8
#define NBUCK 64          // buckets per hash
#define CHUNKS 512        // chunks per batch (NH * NBUCK)
#define BS 64             // bucket/chunk size

#define GAP_MFMA 0.12f    // flag threshold: bf16-R rounding err sigma~0.013 -> 9 sigma

typedef __attribute__((ext_vector_type(8))) short s8_t;   // 8 bf16 (4 VGPRs)
typedef __attribute__((ext_vector_type(4))) float f4_t;   // MFMA C/D

__device__ inline unsigned short bf16_rne(float x) {
    unsigned int u = __float_as_uint(x);
    u += 0x7fffu + ((u >> 16) & 1u);
    return (unsigned short)(u >> 16);
}
__device__ inline unsigned int pack_bf16_pair(float x0, float x1) {
    return (unsigned int)bf16_rne(x0) | ((unsigned int)bf16_rne(x1) << 16);
}
__device__ inline void split_bf16(float x, unsigned short& h, unsigned short& l) {
    h = bf16_rne(x);
    float hf = __uint_as_float(((unsigned int)h) << 16);
    l = bf16_rne(x - hf);
}
// truncation-pack two f32 into (bf16(x0) | bf16(x1)<<16): one v_perm_b32
__device__ inline unsigned int pack_trunc(float x0, float x1) {
    return __builtin_amdgcn_perm(__float_as_uint(x1), __float_as_uint(x0),
                                 0x07060302u);
}
__device__ inline unsigned short bf16_trunc(float x) {
    return (unsigned short)(__float_as_uint(x) >> 16);
}

// lgkm-only barrier: drains LDS writes (required for cross-wave visibility)
// but leaves register-destined global loads and fire-and-forget stores in
// flight (hipcc's __syncthreads emits a full vmcnt(0) drain -- a pure stall
// here since no cross-thread global data is exchanged inside the kernel).
#define BAR_LGKM() do {                                          \
    asm volatile("s_waitcnt lgkmcnt(0)" ::: "memory");           \
    __builtin_amdgcn_s_barrier();                                \
    asm volatile("" ::: "memory");                               \
} while (0)

// ---------------------------------------------------------------------------
// Kernel 1: MFMA hash (GEMM form). A[m=256 outputs (8h x 32i)][k=64] = R bf16,
// B[k=64][n=128 tokens] = qk split hi/lo (2 MFMAs each). Per odd m-tile,
// finalize per-h top-2 of signed candidates [v,-v] via quad butterfly.
// Ambiguous tokens (gap < GAP_MFMA) get flag byte = 1 (no global atomics).
// ---------------------------------------------------------------------------
#define HA_OFF 0          // A (R) : 256 rows x 144 B
#define HQH_OFF 36864     // Q hi  : 128 rows x 144 B
#define HQL_OFF 55296     // Q lo  : 128 rows x 144 B
#define HLDS_TOT 73728
#define HSTR 144          // row stride bytes (64 bf16 + 8 pad)

__global__ __launch_bounds__(256, 2) void hash_kernel(
    const float* __restrict__ qk, const float* __restrict__ rot,
    float* __restrict__ out_buckets, int* __restrict__ bucket_ws,
    unsigned char* __restrict__ flag_ws)
{
    __shared__ char lds[HLDS_TOT];
    int tid = threadIdx.x;
    int wg = blockIdx.x;                       // 512 blocks, 512%8==0
    int orig = ((wg & 7) << 6) + (wg >> 3);    // XCD-contiguous remap
    int b    = orig >> 5;
    int tile = orig & 31;
    int token0 = tile * 128;

    // ---- stage A = R_all: A[m][f] = rot[f*256 + m], bf16 RNE ----
    {
        char* arow = lds + HA_OFF + tid * HSTR;
        #pragma unroll 4
        for (int f = 0; f < 64; f += 2) {
            float r0 = rot[(size_t)f * 256 + tid];
            float r1 = rot[(size_t)(f + 1) * 256 + tid];
            *(unsigned int*)(arow + f * 2) = pack_bf16_pair(r0, r1);
        }
    }
    // ---- stage B = qk tile, split hi/lo ----
    {
        int r = tid >> 1, half = tid & 1;
        int tok = token0 + r;
        const float4* qs = (const float4*)(qk + ((size_t)b * S + tok) * D) + half * 8;
        float xq[32];
        #pragma unroll
        for (int e4 = 0; e4 < 8; ++e4) {
            float4 a = qs[e4];
            xq[e4*4+0]=a.x; xq[e4*4+1]=a.y; xq[e4*4+2]=a.z; xq[e4*4+3]=a.w;
        }
        unsigned int ph[16], pl[16];
        #pragma unroll
        for (int e = 0; e < 16; ++e) {
            unsigned short h0,l0,h1,l1;
            split_bf16(xq[2*e],   h0, l0);
            split_bf16(xq[2*e+1], h1, l1);
            ph[e] = (unsigned int)h0 | ((unsigned int)h1 << 16);
            pl[e] = (unsigned int)l0 | ((unsigned int)l1 << 16);
        }
        char* qh = lds + HQH_OFF + r * HSTR + half * 64;
        char* ql = lds + HQL_OFF + r * HSTR + half * 64;
        #pragma unroll
        for (int e4 = 0; e4 < 4; ++e4) {
            *(uint4*)(qh + e4*16) = make_uint4(ph[e4*4], ph[e4*4+1], ph[e4*4+2], ph[e4*4+3]);
            *(uint4*)(ql + e4*16) = make_uint4(pl[e4*4], pl[e4*4+1], pl[e4*4+2], pl[e4*4+3]);
        }
    }
    __syncthreads();

    int wv   = tid >> 6;
    int lane = tid & 63;
    int quad = lane >> 4;
    int cc   = lane & 15;

    for (int nt = 0; nt < 2; ++nt) {
        int ntg = wv * 2 + nt;            // 0..7 (16-token groups)
        const char* qrh = lds + HQH_OFF + (ntg * 16 + cc) * HSTR + quad * 16;
        const char* qrl = lds + HQL_OFF + (ntg * 16 + cc) * HSTR + quad * 16;
        s8_t bh0 = *(const s8_t*)(qrh);
        s8_t bh1 = *(const s8_t*)(qrh + 64);
        s8_t bl0 = *(const s8_t*)(qrl);
        s8_t bl1 = *(const s8_t*)(qrl + 64);

        float v1 = -3e38f, v2 = -3e38f;
        int i1 = 0;

        for (int mt = 0; mt < 16; ++mt) {
            const char* arow = lds + HA_OFF + (mt * 16 + cc) * HSTR + quad * 16;
            s8_t a0 = *(const s8_t*)(arow);
            s8_t a1 = *(const s8_t*)(arow + 64);
            f4_t acc = (f4_t){0.f, 0.f, 0.f, 0.f};
            acc = __builtin_amdgcn_mfma_f32_16x16x32_bf16(a0, bh0, acc, 0, 0, 0);
            acc = __builtin_amdgcn_mfma_f32_16x16x32_bf16(a1, bh1, acc, 0, 0, 0);
            acc = __builtin_amdgcn_mfma_f32_16x16x32_bf16(a0, bl0, acc, 0, 0, 0);
            acc = __builtin_amdgcn_mfma_f32_16x16x32_bf16(a1, bl1, acc, 0, 0, 0);

            if ((mt & 1) == 0) { v1 = -3e38f; v2 = -3e38f; i1 = 0; }
            int ibase = ((mt & 1) << 4) + (quad << 2);
            #pragma unroll
            for (int r = 0; r < 4; ++r) {
                float vp = acc[r];
                int ip = ibase + r;
                v2 = fmaxf(v2, fminf(vp, v1));
                if (vp > v1) { v1 = vp; i1 = ip; }
                float vn = -vp;
                v2 = fmaxf(v2, fminf(vn, v1));
                if (vn > v1) { v1 = vn; i1 = ip + 32; }
            }

            if (mt & 1) {
                // butterfly merge across the 4 quads (lane bits 4,5)
                #pragma unroll
                for (int off = 16; off <= 32; off <<= 1) {
                    float ov1 = __shfl_xor(v1, off, 64);
                    float ov2 = __shfl_xor(v2, off, 64);
                    int   oi1 = __shfl_xor(i1, off, 64);
                    float nv2 = fmaxf(fmaxf(v2, ov2), fminf(v1, ov1));
                    if (ov1 > v1) { v1 = ov1; i1 = oi1; }
                    v2 = nv2;
                }
                if (quad == 0) {
                    int h = mt >> 1;
                    int tok = token0 + ntg * 16 + cc;
                    size_t idx = (size_t)(b * NH + h) * S + tok;
                    bucket_ws[idx] = i1;
                    out_buckets[idx] = (float)(i1 + h * NBUCK);
                    flag_ws[idx] = (v1 - v2 < GAP_MFMA) ? 1 : 0;  // fire-and-forget
                }
            }
        }
    }
}

// ---------------------------------------------------------------------------
// Kernel 1b: exact f64 recompute for flagged tokens.
// ---------------------------------------------------------------------------
__global__ __launch_bounds__(256) void hash_fixup_kernel(
    const float* __restrict__ qk, const float* __restrict__ rot,
    const unsigned char* __restrict__ flag_ws,
    float* __restrict__ out_buckets, int* __restrict__ bucket_ws)
{
    __shared__ int list[2048];
    __shared__ int cnt;
    int tid = threadIdx.x;
    if (tid == 0) cnt = 0;
    __syncthreads();

    int base = blockIdx.x * 2048;
    for (int i = tid; i < 2048; i += 256) {
        if (flag_ws[base + i]) {
            int slot = atomicAdd(&cnt, 1);    // LDS atomic (block-local)
            list[slot] = base + i;
        }
    }
    __syncthreads();
    int n = cnt;

    for (int j = tid; j < n; j += 256) {
        int gid = list[j];
        int bh = gid >> 12, t = gid & (S - 1);
        int b = bh >> 3, h = bh & 7;
        const float* row = qk + ((size_t)b * S + t) * D;

        double acc[32];
        #pragma unroll
        for (int i = 0; i < 32; ++i) acc[i] = 0.0;
        for (int f = 0; f < 64; ++f) {
            double x = (double)row[f];
            const float* rr = rot + f * (NH * 32) + h * 32;
            #pragma unroll
            for (int i = 0; i < 32; ++i)
                acc[i] = __fma_rn(x, (double)rr[i], acc[i]);
        }
        double best = acc[0]; int bi = 0;
        double worst = acc[0]; int wi = 0;
        #pragma unroll
        for (int i = 1; i < 32; ++i) {
            if (acc[i] > best)  { best = acc[i]; bi = i; }
            if (acc[i] < worst) { worst = acc[i]; wi = i; }
        }
        int bucket = (-worst > best) ? (32 + wi) : bi;
        bucket_ws[gid] = bucket;
        out_buckets[gid] = (float)(bucket + h * NBUCK);
    }
}

// ---------------------------------------------------------------------------
// Kernel 2: parallel stable counting sort per (b,h). 512 threads (8 waves):
// halves the serial scatter depth vs the 4-wave version (grid is only 128
// blocks -- half the CUs idle -- so per-block latency is what matters).
// ---------------------------------------------------------------------------
__global__ __launch_bounds__(512) void sort_kernel(
    const int* __restrict__ bucket_ws, int* __restrict__ st_ws)
{
    __shared__ int sb[S];
    __shared__ int hist[8][64];
    __shared__ int bpref[64];
    __shared__ int woff[8][64];

    int tid  = threadIdx.x;
    int wv   = tid >> 6;
    int lane = tid & 63;
    int base = blockIdx.x * S;

    hist[wv][lane] = 0;
    __syncthreads();

    int qbase = wv * 512;
    #pragma unroll
    for (int i = 0; i < 8; ++i) {
        int t = qbase + i * 64 + lane;
        int v = bucket_ws[base + t];
        sb[t] = v;
        atomicAdd(&hist[wv][v], 1);
    }
    __syncthreads();

    if (wv == 0) {
        int total = 0;
        #pragma unroll
        for (int w = 0; w < 8; ++w) total += hist[w][lane];
        int x = total;
        #pragma unroll
        for (int off = 1; off < 64; off <<= 1) {
            int y = __shfl_up(x, off, 64);
            if (lane >= off) x += y;
        }
        bpref[lane] = x - total;
    }
    __syncthreads();
    {
        int o = bpref[lane];
        for (int w2 = 0; w2 < 8; ++w2) {
            if (w2 < wv) o += hist[w2][lane];
        }
        woff[wv][lane] = o;
    }
    __syncthreads();

    for (int g = 0; g < 8; ++g) {
        int t = qbase + g * 64 + lane;
        int v = sb[t];

        unsigned long long m = ~0ULL;
        #pragma unroll
        for (int bit = 0; bit < 6; ++bit) {
            unsigned long long bm = __ballot((v >> bit) & 1);
            m &= ((v >> bit) & 1) ? bm : ~bm;
        }
        unsigned long long below = (lane == 63) ? ~0ULL >> 1
                                 : ((1ULL << lane) - 1ULL);
        int rank = __popcll(m & below);
        int cnt  = __popcll(m);

        int pos = woff[wv][v] + rank;
        st_ws[base + pos] = t;

        if ((m & below) == 0ULL)
            woff[wv][v] += cnt;
        __builtin_amdgcn_s_waitcnt(0);
    }
}

// ---------------------------------------------------------------------------
// Kernel 3: per-chunk attention.
// Key-order permutation kappa: key k = t*16+cc lives at POSITION p = cc*8+t
// (p&7 = t, p>>3 = cc) in both P rows and VtP rows. The PV dot over keys is
// order-invariant, so only the two STAGING sites change; all MFMA-phase
// addressing is identical. Payoff: P write = 4 x ds_write_b128 per thread
// (bank-balanced) instead of 32 x ds_write_b16 (4-way conflicted).
// Self-mask is STATIC: sorted positions within (b,h) are a permutation ->
// token equality <=> key index == query index (t==wv && cc==quad*4+g).
// K is staged RAW (unnormalized); per-KEY inv-norm is folded into the
// log2-domain scale (nrm_s holds 1/max(|k|,1e-12); per-query 1/sum lives in
// a separate pinv_s to avoid cross-wave WAR on nrm_s).
// LDS (37120 B -> 4 blocks/CU):
//   K  [128][144B] @0        -- raw keys bf16; rows overlaid by P[64][272B]
//   VtP[64][272B]  @18432    -- V^T, kappa order, dword = positions(2d,2d+1)
//   nrm @35840 (512) inv-norms | tkx @36352 (512) | pinv @36864 (256)
// ---------------------------------------------------------------------------
#define OFF_VT 18432
#define OFF_NRM 35840
#define OFF_TKX 36352
#define OFF_PINV 36864
#define LDS_TOT 37120
#define KSTRB 144     // K row stride bytes (72 bf16), 16B-aligned, 36 dw
#define PSTRB 272     // P row stride bytes (136 bf16), 68 dw
#define VSTRD 68      // VtP row stride in dwords (272 B)

__global__ __launch_bounds__(256, 4) void attn_kernel(
    const float* __restrict__ qk, const float* __restrict__ v,
    const int* __restrict__ st_ws,
    __hip_bfloat16* __restrict__ o_ws, float* __restrict__ logits_ws)
{
    __shared__ char lds[LDS_TOT];
    float* nrm_s  = (float*)(lds + OFF_NRM);
    int*   tkx    = (int*)(lds + OFF_TKX);
    float* pinv_s = (float*)(lds + OFF_PINV);
    unsigned int* VtP = (unsigned int*)(lds + OFF_VT);

    int tid = threadIdx.x;
    // XCD-contiguous swizzle: resident blocks share one batch's working set.
    int wg = blockIdx.x;
    int orig = ((wg & 7) << 10) + (wg >> 3);
    int c = orig & (CHUNKS - 1);
    int b = orig >> 9;
    int h = c >> 6;
    int sbase = b * (NH * S);
    int cprev = (c + CHUNKS - 1) & (CHUNKS - 1);

    // ---- issue V gather loads early (kappa order); consumed post-QK ----
    int av_ = tid & 63, sub_ = tid >> 6;      // av_ = position pair, sub_ = dim/4
    int k0 = 32 * (av_ & 3) + (av_ >> 2);     // key at position 2*av_
    int k1 = k0 + 16;                          // key at position 2*av_+1
    int chv = ((av_ & 3) < 2) ? c : cprev;     // both keys in same chunk
    int tokv0 = st_ws[sbase + chv * BS + (k0 & 63)];
    int tokv1 = st_ws[sbase + chv * BS + (k1 & 63)];
    const float4* vp0 = (const float4*)(v + ((size_t)b * S + tokv0) * D + sub_ * 16);
    const float4* vp1 = (const float4*)(v + ((size_t)b * S + tokv1) * D + sub_ * 16);
    float4 vr0[4], vr1[4];
    #pragma unroll
    for (int e4 = 0; e4 < 4; ++e4) { vr0[e4] = vp0[e4]; vr1[e4] = vp1[e4]; }

    // ---- stage K RAW (bf16 trunc); store inv-norm + token index ----
    {
        int r = tid >> 1, half = tid & 1;
        int ch = (r < 64) ? c : cprev;
        int tok = st_ws[sbase + ch * BS + (r & 63)];
        if (!half) tkx[r] = tok;
        const float4* qs = (const float4*)(qk + ((size_t)b * S + tok) * D) + half * 8;
        float xq[32];
        #pragma unroll
        for (int e4 = 0; e4 < 8; ++e4) {
            float4 a = qs[e4];
            xq[e4*4+0]=a.x; xq[e4*4+1]=a.y; xq[e4*4+2]=a.z; xq[e4*4+3]=a.w;
        }
        float ss = 0.f;
        #pragma unroll
        for (int e = 0; e < 32; ++e) ss += xq[e]*xq[e];
        ss += __shfl_xor(ss, 1);
        float inv = 1.0f / fmaxf(sqrtf(ss), 1e-12f);
        if (!half) nrm_s[r] = inv;

        unsigned int pk[16];
        #pragma unroll
        for (int e = 0; e < 16; ++e)
            pk[e] = pack_trunc(xq[2*e], xq[2*e+1]);
        char* kb = lds + r * KSTRB + half * 64;
        #pragma unroll
        for (int e4 = 0; e4 < 4; ++e4)
            *(uint4*)(kb + e4*16) = make_uint4(pk[e4*4], pk[e4*4+1], pk[e4*4+2], pk[e4*4+3]);
    }
    BAR_LGKM();   // K/tkx/nrm visible; V loads legally still in flight

    int wv   = tid >> 6;
    int lane = tid & 63;
    int quad = lane >> 4;
    int cc   = lane & 15;

    // ---- dots: QK^T via bf16 MFMA (raw x raw) ----
    int qrow = wv * 16 + cc;
    f4_t acc[8];
    #pragma unroll
    for (int t = 0; t < 8; ++t) acc[t] = (f4_t){0.f,0.f,0.f,0.f};

    __builtin_amdgcn_s_setprio(1);
    #pragma unroll
    for (int kc = 0; kc < 2; ++kc) {
        int aoff = kc * 64 + quad * 16;
        s8_t av = *(const s8_t*)(lds + qrow * KSTRB + aoff);
        #pragma unroll
        for (int t = 0; t < 8; ++t) {
            s8_t bv = *(const s8_t*)(lds + (t * 16 + cc) * KSTRB + aoff);
            acc[t] = __builtin_amdgcn_mfma_f32_16x16x32_bf16(av, bv, acc[t], 0, 0, 0);
        }
    }
    __builtin_amdgcn_s_setprio(0);

    // ---- pack + write V^T (kappa order; loads arrived under QK) ----
    {
        float x0[16], x1[16];
        #pragma unroll
        for (int e4 = 0; e4 < 4; ++e4) {
            float4 p0 = vr0[e4], p1 = vr1[e4];
            x0[e4*4+0]=p0.x; x0[e4*4+1]=p0.y; x0[e4*4+2]=p0.z; x0[e4*4+3]=p0.w;
            x1[e4*4+0]=p1.x; x1[e4*4+1]=p1.y; x1[e4*4+2]=p1.z; x1[e4*4+3]=p1.w;
        }
        #pragma unroll
        for (int e = 0; e < 16; ++e) {
            int dd = sub_ * 16 + e;
            VtP[dd * VSTRD + av_] = pack_trunc(x0[e], x1[e]);
        }
    }

    // ---- scale (per-key inv-norm, log2 domain) + static self-mask ----
    float invsc[8];
    #pragma unroll
    for (int t = 0; t < 8; ++t)
        invsc[t] = nrm_s[t * 16 + cc] * 0.18033688f;   // 0.125 * log2(e) / |k|

    #pragma unroll
    for (int t = 0; t < 8; ++t) {
        #pragma unroll
        for (int g = 0; g < 4; ++g)
            acc[t][g] = acc[t][g] * invsc[t];
        if (t == wv) {          // scalar-uniform branch: self keys live here
            #pragma unroll
            for (int g = 0; g < 4; ++g)
                if (cc == quad * 4 + g) acc[t][g] = -3e5f;
        }
    }

    float mx[4];
    #pragma unroll
    for (int g = 0; g < 4; ++g) {
        float m = acc[0][g];
        #pragma unroll
        for (int t = 1; t < 8; ++t) m = fmaxf(m, acc[t][g]);
        mx[g] = m;
    }
    #pragma unroll
    for (int msk = 1; msk <= 8; msk <<= 1)
        #pragma unroll
        for (int g = 0; g < 4; ++g) mx[g] = fmaxf(mx[g], __shfl_xor(mx[g], msk, 64));

    float sm[4] = {0.f, 0.f, 0.f, 0.f};
    #pragma unroll
    for (int t = 0; t < 8; ++t)
        #pragma unroll
        for (int g = 0; g < 4; ++g) {
            float p = __builtin_amdgcn_exp2f(acc[t][g] - mx[g]);
            acc[t][g] = p;
            sm[g] += p;
        }
    #pragma unroll
    for (int msk = 1; msk <= 8; msk <<= 1)
        #pragma unroll
        for (int g = 0; g < 4; ++g) sm[g] += __shfl_xor(sm[g], msk, 64);

    int tqi[4];
    #pragma unroll
    for (int g = 0; g < 4; ++g) tqi[g] = tkx[wv * 16 + quad * 4 + g];

    if (cc == 0) {
        #pragma unroll
        for (int g = 0; g < 4; ++g) {
            int q = wv * 16 + quad * 4 + g;
            pinv_s[q] = 1.0f / sm[g];
            logits_ws[sbase + h * S + tqi[g]] =
                0.69314718f * (mx[g] + __log2f(sm[g]));
        }
    }

    // ---- P -> bf16 LDS in kappa order: 4 x b128/thread, overlaying K ----
    BAR_LGKM();   // all QK reads of K done; logits store stays in flight
    #pragma unroll
    for (int g = 0; g < 4; ++g) {
        int q = wv * 16 + quad * 4 + g;
        uint4 w;
        w.x = pack_trunc(acc[0][g], acc[1][g]);   // positions 8cc+0,1 = keys 0*16+cc,1*16+cc
        w.y = pack_trunc(acc[2][g], acc[3][g]);
        w.z = pack_trunc(acc[4][g], acc[5][g]);
        w.w = pack_trunc(acc[6][g], acc[7][g]);
        *(uint4*)(lds + q * PSTRB + cc * 16) = w;
    }

    // ---- PV as O^T = V^T * P (both sides in kappa key order) ----
    f4_t oaccT[4];
    #pragma unroll
    for (int n = 0; n < 4; ++n) oaccT[n] = (f4_t){0.f,0.f,0.f,0.f};

    __builtin_amdgcn_s_setprio(1);
    #pragma unroll
    for (int kc = 0; kc < 4; ++kc) {
        int koff = kc * 64 + quad * 16;   // byte offset: position p at byte 2p
        s8_t pb = *(const s8_t*)(lds + (wv * 16 + cc) * PSTRB + koff);
        #pragma unroll
        for (int n = 0; n < 4; ++n) {
            s8_t va = *(const s8_t*)((const char*)(VtP + (n * 16 + cc) * VSTRD) + koff);
            oaccT[n] = __builtin_amdgcn_mfma_f32_16x16x32_bf16(va, pb, oaccT[n], 0, 0, 0);
        }
    }
    __builtin_amdgcn_s_setprio(0);

    // ---- write O (bf16 trunc, scaled by deferred pinv): 4 x 8B stores ----
    {
        int q = wv * 16 + cc;
        int tok = tkx[q];                 // tkx region not overlaid by P
        float pq = pinv_s[q];
        __hip_bfloat16* op = o_ws + ((size_t)(sbase + h * S + tok)) * D + quad * 4;
        #pragma unroll
        for (int n = 0; n < 4; ++n) {
            uint2 pk2;
            pk2.x = pack_trunc(oaccT[n][0] * pq, oaccT[n][1] * pq);
            pk2.y = pack_trunc(oaccT[n][2] * pq, oaccT[n][3] * pq);
            *(uint2*)(op + n * 16) = pk2;
        }
    }
}

// ---------------------------------------------------------------------------
// Kernel 4: combine hash rounds with softmax(logits) weights. o_ws is bf16.
// ---------------------------------------------------------------------------
__global__ __launch_bounds__(256) void combine_kernel(
    const __hip_bfloat16* __restrict__ o_ws, const float* __restrict__ logits_ws,
    float* __restrict__ out)
{
    int gid = blockIdx.x * 256 + threadIdx.x;
    int token = gid >> 3;          // b*S + t
    int d8 = gid & 7;
    int b = token >> 12;
    int t = token & (S - 1);
    int base = b * (NH * S) + t;

    float l[8];
    #pragma unroll
    for (int hh = 0; hh < 8; ++hh) l[hh] = logits_ws[base + hh * S];
    float m = l[0];
    #pragma unroll
    for (int hh = 1; hh < 8; ++hh) m = fmaxf(m, l[hh]);
    float w[8]; float ssum = 0.f;
    #pragma unroll
    for (int hh = 0; hh < 8; ++hh) { w[hh] = __expf(l[hh] - m); ssum += w[hh]; }
    float inv = 1.0f / ssum;

    float accv[8] = {0,0,0,0,0,0,0,0};
    #pragma unroll
    for (int hh = 0; hh < 8; ++hh) {
        uint4 pk = *(const uint4*)(o_ws + (size_t)(base + hh * S) * D + d8 * 8);
        float wh = w[hh] * inv;
        unsigned int ws_[4] = {pk.x, pk.y, pk.z, pk.w};
        #pragma unroll
        for (int e = 0; e < 4; ++e) {
            float lo = __uint_as_float(ws_[e] << 16);
            float hi = __uint_as_float(ws_[e] & 0xffff0000u);
            accv[2*e]   += wh * lo;
            accv[2*e+1] += wh * hi;
        }
    }
    float4* op = (float4*)(out + (size_t)token * D + d8 * 8);
    op[0] = make_float4(accv[0], accv[1], accv[2], accv[3]);
    op[1] = make_float4(accv[4], accv[5], accv[6], accv[7]);
}

// ---------------------------------------------------------------------------
extern "C" void kernel_launch(void* const* d_in, const int* in_sizes, int n_in,
                              void* d_out, int out_size, void* d_ws, size_t ws_size,
                              hipStream_t stream) {
    const float* qk  = (const float*)d_in[0];
    const float* v   = (const float*)d_in[1];
    const float* rot = (const float*)d_in[2];

    float* out         = (float*)d_out;
    float* out_buckets = out + (size_t)B * S * D;

    int*   bucket_ws = (int*)d_ws;                              // 524288 ints
    int*   st_ws     = bucket_ws + (size_t)B * NH * S;          // 524288 ints
    float* logits_ws = (float*)(st_ws + (size_t)B * NH * S);    // 524288 f32
    __hip_bfloat16* o_ws = (__hip_bfloat16*)(logits_ws + (size_t)B * NH * S); // 64 MB
    unsigned char* flag_ws = (unsigned char*)(o_ws + (size_t)B * NH * S * D); // 512 KB

    hash_kernel<<<B * 32, 256, 0, stream>>>(qk, rot, out_buckets, bucket_ws,
                                            flag_ws);
    hash_fixup_kernel<<<(B * NH * S) / 2048, 256, 0, stream>>>(
        qk, rot, flag_ws, out_buckets, bucket_ws);
    sort_kernel<<<B * NH, 512, 0, stream>>>(bucket_ws, st_ws);
    attn_kernel<<<B * CHUNKS, 256, 0, stream>>>(qk, v, st_ws, o_ws, logits_ws);
    combine_kernel<<<(B * S * 8) / 256, 256, 0, stream>>>(o_ws, logits_ws, out);
}

// Round 4
// 194.781 us; speedup vs baseline: 1.1909x; 1.1306x over previous
//
#include <hip/hip_runtime.h>
#include <hip/hip_bf16.h>
#include <math.h>

// Problem constants
#define B 16
#define S 4096
#define D 64
#define NH 8
#define NBUCK 64          // buckets per hash
#define CHUNKS 512        // chunks per batch (NH * NBUCK)
#define BS 64             // bucket/chunk size

#define GAP_MFMA 0.12f    // flag threshold: bf16-R rounding err sigma~0.013 -> 9 sigma

typedef __attribute__((ext_vector_type(8))) short s8_t;   // 8 bf16 (4 VGPRs)
typedef __attribute__((ext_vector_type(4))) float f4_t;   // MFMA C/D
typedef __attribute__((ext_vector_type(2))) unsigned int u32x2;

__device__ inline unsigned short bf16_rne(float x) {
    unsigned int u = __float_as_uint(x);
    u += 0x7fffu + ((u >> 16) & 1u);
    return (unsigned short)(u >> 16);
}
__device__ inline unsigned int pack_bf16_pair(float x0, float x1) {
    return (unsigned int)bf16_rne(x0) | ((unsigned int)bf16_rne(x1) << 16);
}
__device__ inline void split_bf16(float x, unsigned short& h, unsigned short& l) {
    h = bf16_rne(x);
    float hf = __uint_as_float(((unsigned int)h) << 16);
    l = bf16_rne(x - hf);
}
// truncation-pack two f32 into (bf16(x0) | bf16(x1)<<16): one v_perm_b32
__device__ inline unsigned int pack_trunc(float x0, float x1) {
    return __builtin_amdgcn_perm(__float_as_uint(x1), __float_as_uint(x0),
                                 0x07060302u);
}
__device__ inline unsigned short bf16_trunc(float x) {
    return (unsigned short)(__float_as_uint(x) >> 16);
}

// lgkm-only barrier: drains LDS writes but leaves register-destined global
// loads and fire-and-forget stores in flight.
#define BAR_LGKM() do {                                          \
    asm volatile("s_waitcnt lgkmcnt(0)" ::: "memory");           \
    __builtin_amdgcn_s_barrier();                                \
    asm volatile("" ::: "memory");                               \
} while (0)

// ds_read_b64_tr_b16 with compile-time offset. Per-lane addr = base + lane*8;
// each 16-lane group reads its 128B (4x16 bf16) tile, delivered column-major:
// lane l receives elems (l&15) + j*16 (+ (l>>4)*64 from its addr). gfx9+
// shared aperture is 4GB-aligned, so truncating the flat address yields the
// LDS byte offset.
template<int OFF>
__device__ inline u32x2 tr_read(unsigned int vaddr) {
    u32x2 d;
    asm volatile("ds_read_b64_tr_b16 %0, %1 offset:%c2"
                 : "=v"(d) : "v"(vaddr), "i"(OFF));
    return d;
}

// ---------------------------------------------------------------------------
// Kernel 1: MFMA hash (GEMM form). A[m=256 outputs (8h x 32i)][k=64] = R bf16,
// B[k=64][n=128 tokens] = qk split hi/lo (2 MFMAs each). Per odd m-tile,
// finalize per-h top-2 of signed candidates [v,-v] via quad butterfly.
// qk staging is 4-lanes-per-row coalesced (16 segments/instr, not 64).
// ---------------------------------------------------------------------------
#define HA_OFF 0          // A (R) : 256 rows x 144 B
#define HQH_OFF 36864     // Q hi  : 128 rows x 144 B
#define HQL_OFF 55296     // Q lo  : 128 rows x 144 B
#define HLDS_TOT 73728
#define HSTR 144          // row stride bytes (64 bf16 + 8 pad)

__global__ __launch_bounds__(256, 2) void hash_kernel(
    const float* __restrict__ qk, const float* __restrict__ rot,
    float* __restrict__ out_buckets, int* __restrict__ bucket_ws,
    unsigned char* __restrict__ flag_ws)
{
    __shared__ char lds[HLDS_TOT];
    int tid = threadIdx.x;
    int wg = blockIdx.x;                       // 512 blocks, 512%8==0
    int orig = ((wg & 7) << 6) + (wg >> 3);    // XCD-contiguous remap
    int b    = orig >> 5;
    int tile = orig & 31;
    int token0 = tile * 128;

    // ---- stage A = R_all: A[m][f] = rot[f*256 + m], bf16 RNE ----
    {
        char* arow = lds + HA_OFF + tid * HSTR;
        #pragma unroll 4
        for (int f = 0; f < 64; f += 2) {
            float r0 = rot[(size_t)f * 256 + tid];
            float r1 = rot[(size_t)(f + 1) * 256 + tid];
            *(unsigned int*)(arow + f * 2) = pack_bf16_pair(r0, r1);
        }
    }
    // ---- stage B = qk tile, split hi/lo; coalesced 4-lanes-per-row ----
    {
        int wv0   = tid >> 6;
        int lane0 = tid & 63;
        int s_ = lane0 & 3;
        int rowA = wv0 * 32 + (lane0 >> 2);
        int rowB = rowA + 16;
        const float4* qA = (const float4*)(qk + ((size_t)b * S + token0 + rowA) * D);
        const float4* qB = (const float4*)(qk + ((size_t)b * S + token0 + rowB) * D);
        float4 a4[4], b4[4];
        #pragma unroll
        for (int n = 0; n < 4; ++n) { a4[n] = qA[n * 4 + s_]; b4[n] = qB[n * 4 + s_]; }

        char* qhA = lds + HQH_OFF + rowA * HSTR;
        char* qlA = lds + HQL_OFF + rowA * HSTR;
        char* qhB = lds + HQH_OFF + rowB * HSTR;
        char* qlB = lds + HQL_OFF + rowB * HSTR;
        #pragma unroll
        for (int n = 0; n < 4; ++n) {
            float fa[4] = {a4[n].x, a4[n].y, a4[n].z, a4[n].w};
            float fb[4] = {b4[n].x, b4[n].y, b4[n].z, b4[n].w};
            unsigned short h[4], l[4];
            #pragma unroll
            for (int e = 0; e < 4; ++e) split_bf16(fa[e], h[e], l[e]);
            *(uint2*)(qhA + n * 32 + s_ * 8) =
                make_uint2((unsigned)h[0] | ((unsigned)h[1] << 16),
                           (unsigned)h[2] | ((unsigned)h[3] << 16));
            *(uint2*)(qlA + n * 32 + s_ * 8) =
                make_uint2((unsigned)l[0] | ((unsigned)l[1] << 16),
                           (unsigned)l[2] | ((unsigned)l[3] << 16));
            #pragma unroll
            for (int e = 0; e < 4; ++e) split_bf16(fb[e], h[e], l[e]);
            *(uint2*)(qhB + n * 32 + s_ * 8) =
                make_uint2((unsigned)h[0] | ((unsigned)h[1] << 16),
                           (unsigned)h[2] | ((unsigned)h[3] << 16));
            *(uint2*)(qlB + n * 32 + s_ * 8) =
                make_uint2((unsigned)l[0] | ((unsigned)l[1] << 16),
                           (unsigned)l[2] | ((unsigned)l[3] << 16));
        }
    }
    __syncthreads();

    int wv   = tid >> 6;
    int lane = tid & 63;
    int quad = lane >> 4;
    int cc   = lane & 15;

    for (int nt = 0; nt < 2; ++nt) {
        int ntg = wv * 2 + nt;            // 0..7 (16-token groups)
        const char* qrh = lds + HQH_OFF + (ntg * 16 + cc) * HSTR + quad * 16;
        const char* qrl = lds + HQL_OFF + (ntg * 16 + cc) * HSTR + quad * 16;
        s8_t bh0 = *(const s8_t*)(qrh);
        s8_t bh1 = *(const s8_t*)(qrh + 64);
        s8_t bl0 = *(const s8_t*)(qrl);
        s8_t bl1 = *(const s8_t*)(qrl + 64);

        float v1 = -3e38f, v2 = -3e38f;
        int i1 = 0;

        for (int mt = 0; mt < 16; ++mt) {
            const char* arow = lds + HA_OFF + (mt * 16 + cc) * HSTR + quad * 16;
            s8_t a0 = *(const s8_t*)(arow);
            s8_t a1 = *(const s8_t*)(arow + 64);
            f4_t acc = (f4_t){0.f, 0.f, 0.f, 0.f};
            acc = __builtin_amdgcn_mfma_f32_16x16x32_bf16(a0, bh0, acc, 0, 0, 0);
            acc = __builtin_amdgcn_mfma_f32_16x16x32_bf16(a1, bh1, acc, 0, 0, 0);
            acc = __builtin_amdgcn_mfma_f32_16x16x32_bf16(a0, bl0, acc, 0, 0, 0);
            acc = __builtin_amdgcn_mfma_f32_16x16x32_bf16(a1, bl1, acc, 0, 0, 0);

            if ((mt & 1) == 0) { v1 = -3e38f; v2 = -3e38f; i1 = 0; }
            int ibase = ((mt & 1) << 4) + (quad << 2);
            #pragma unroll
            for (int r = 0; r < 4; ++r) {
                float vp = acc[r];
                int ip = ibase + r;
                v2 = fmaxf(v2, fminf(vp, v1));
                if (vp > v1) { v1 = vp; i1 = ip; }
                float vn = -vp;
                v2 = fmaxf(v2, fminf(vn, v1));
                if (vn > v1) { v1 = vn; i1 = ip + 32; }
            }

            if (mt & 1) {
                // butterfly merge across the 4 quads (lane bits 4,5)
                #pragma unroll
                for (int off = 16; off <= 32; off <<= 1) {
                    float ov1 = __shfl_xor(v1, off, 64);
                    float ov2 = __shfl_xor(v2, off, 64);
                    int   oi1 = __shfl_xor(i1, off, 64);
                    float nv2 = fmaxf(fmaxf(v2, ov2), fminf(v1, ov1));
                    if (ov1 > v1) { v1 = ov1; i1 = oi1; }
                    v2 = nv2;
                }
                if (quad == 0) {
                    int h = mt >> 1;
                    int tok = token0 + ntg * 16 + cc;
                    size_t idx = (size_t)(b * NH + h) * S + tok;
                    bucket_ws[idx] = i1;
                    out_buckets[idx] = (float)(i1 + h * NBUCK);
                    flag_ws[idx] = (v1 - v2 < GAP_MFMA) ? 1 : 0;  // fire-and-forget
                }
            }
        }
    }
}

// ---------------------------------------------------------------------------
// Kernel 1b: exact f64 recompute for flagged tokens.
// ---------------------------------------------------------------------------
__global__ __launch_bounds__(256) void hash_fixup_kernel(
    const float* __restrict__ qk, const float* __restrict__ rot,
    const unsigned char* __restrict__ flag_ws,
    float* __restrict__ out_buckets, int* __restrict__ bucket_ws)
{
    __shared__ int list[2048];
    __shared__ int cnt;
    int tid = threadIdx.x;
    if (tid == 0) cnt = 0;
    __syncthreads();

    int base = blockIdx.x * 2048;
    for (int i = tid; i < 2048; i += 256) {
        if (flag_ws[base + i]) {
            int slot = atomicAdd(&cnt, 1);    // LDS atomic (block-local)
            list[slot] = base + i;
        }
    }
    __syncthreads();
    int n = cnt;

    for (int j = tid; j < n; j += 256) {
        int gid = list[j];
        int bh = gid >> 12, t = gid & (S - 1);
        int b = bh >> 3, h = bh & 7;
        const float* row = qk + ((size_t)b * S + t) * D;

        double acc[32];
        #pragma unroll
        for (int i = 0; i < 32; ++i) acc[i] = 0.0;
        for (int f = 0; f < 64; ++f) {
            double x = (double)row[f];
            const float* rr = rot + f * (NH * 32) + h * 32;
            #pragma unroll
            for (int i = 0; i < 32; ++i)
                acc[i] = __fma_rn(x, (double)rr[i], acc[i]);
        }
        double best = acc[0]; int bi = 0;
        double worst = acc[0]; int wi = 0;
        #pragma unroll
        for (int i = 1; i < 32; ++i) {
            if (acc[i] > best)  { best = acc[i]; bi = i; }
            if (acc[i] < worst) { worst = acc[i]; wi = i; }
        }
        int bucket = (-worst > best) ? (32 + wi) : bi;
        bucket_ws[gid] = bucket;
        out_buckets[gid] = (float)(bucket + h * NBUCK);
    }
}

// ---------------------------------------------------------------------------
// Kernel 2: parallel stable counting sort per (b,h). 512 threads (8 waves).
// (Removed the per-iteration full s_waitcnt(0) drain: all intra-loop deps are
// wave-local LDS ops the compiler already orders; the scattered st_ws store
// needs no ordering.)
// ---------------------------------------------------------------------------
__global__ __launch_bounds__(512) void sort_kernel(
    const int* __restrict__ bucket_ws, int* __restrict__ st_ws)
{
    __shared__ int sb[S];
    __shared__ int hist[8][64];
    __shared__ int bpref[64];
    __shared__ int woff[8][64];

    int tid  = threadIdx.x;
    int wv   = tid >> 6;
    int lane = tid & 63;
    int base = blockIdx.x * S;

    hist[wv][lane] = 0;
    __syncthreads();

    int qbase = wv * 512;
    #pragma unroll
    for (int i = 0; i < 8; ++i) {
        int t = qbase + i * 64 + lane;
        int v = bucket_ws[base + t];
        sb[t] = v;
        atomicAdd(&hist[wv][v], 1);
    }
    __syncthreads();

    if (wv == 0) {
        int total = 0;
        #pragma unroll
        for (int w = 0; w < 8; ++w) total += hist[w][lane];
        int x = total;
        #pragma unroll
        for (int off = 1; off < 64; off <<= 1) {
            int y = __shfl_up(x, off, 64);
            if (lane >= off) x += y;
        }
        bpref[lane] = x - total;
    }
    __syncthreads();
    {
        int o = bpref[lane];
        for (int w2 = 0; w2 < 8; ++w2) {
            if (w2 < wv) o += hist[w2][lane];
        }
        woff[wv][lane] = o;
    }
    __syncthreads();

    for (int g = 0; g < 8; ++g) {
        int t = qbase + g * 64 + lane;
        int v = sb[t];

        unsigned long long m = ~0ULL;
        #pragma unroll
        for (int bit = 0; bit < 6; ++bit) {
            unsigned long long bm = __ballot((v >> bit) & 1);
            m &= ((v >> bit) & 1) ? bm : ~bm;
        }
        unsigned long long below = (lane == 63) ? ~0ULL >> 1
                                 : ((1ULL << lane) - 1ULL);
        int rank = __popcll(m & below);
        int cnt  = __popcll(m);

        int pos = woff[wv][v] + rank;
        st_ws[base + pos] = t;

        if ((m & below) == 0ULL)
            woff[wv][v] += cnt;
    }
}

// ---------------------------------------------------------------------------
// Kernel 3: per-chunk attention.
// kappa position order: key k = t*16+cc lives at POSITION p = cc*8+t; P and
// V both use p, QK/K rows use sorted index directly. Self-mask is static.
// K gather: coalesced, 4 lanes per row (lane covers dims n*16+(lane&3)*4).
// V gather: coalesced the same way; V stored in tr-subtiled layout:
//   32 blocks of 544 B, block bi = kc*8 + n*2 + r  (kc=p>>5, n=dim>>4,
//   r=(p>>2)&1); elem a in block: dim = n*16+(a&15),
//   pos = kc*32 + 8*(a>>6) + 4r + ((a>>4)&3).
//   One lane's 16B row-chunk = one contiguous 8B store pair.
// PV A-operand read with ds_read_b64_tr_b16 (2 reads per fragment, one
// address reg + immediate offsets; lgkmcnt(0)+sched_barrier before MFMA).
// Load-issue order: K tokens/rows FIRST, then V -- so K processing waits at
// vmcnt(10) and V stays in flight under QK (the R2 version had this
// backwards and silently drained vmcnt to 0).
// LDS (37120 B -> 4 blocks/CU):
//   K  [128][144B] @0        -- raw keys bf16; rows overlaid by P[64][272B]
//   Vtr 32 x 544B  @18432    -- tr-subtiled V (17408 B)
//   nrm @35840 (512) inv-norms | tkx @36352 (512) | pinv @36864 (256)
// ---------------------------------------------------------------------------
#define OFF_VT 18432
#define OFF_NRM 35840
#define OFF_TKX 36352
#define OFF_PINV 36864
#define LDS_TOT 37120
#define KSTRB 144     // K row stride bytes (72 bf16), 16B-aligned, 36 dw
#define PSTRB 272     // P row stride bytes (136 bf16), 68 dw

// one PV phase: P b128 + 8 tr reads + 4 MFMAs
template<int KC>
__device__ inline void pv_step(const char* lds, unsigned vaddr,
                               int wv, int cc, int quad, f4_t* oaccT)
{
    s8_t pb = *(const s8_t*)(lds + (wv * 16 + cc) * PSTRB + KC * 64 + quad * 16);
    u32x2 t00 = tr_read<KC * 4352 +    0>(vaddr);
    u32x2 t01 = tr_read<KC * 4352 +  544>(vaddr);
    u32x2 t10 = tr_read<KC * 4352 + 1088>(vaddr);
    u32x2 t11 = tr_read<KC * 4352 + 1632>(vaddr);
    u32x2 t20 = tr_read<KC * 4352 + 2176>(vaddr);
    u32x2 t21 = tr_read<KC * 4352 + 2720>(vaddr);
    u32x2 t30 = tr_read<KC * 4352 + 3264>(vaddr);
    u32x2 t31 = tr_read<KC * 4352 + 3808>(vaddr);
    asm volatile("s_waitcnt lgkmcnt(0)" ::: "memory");
    __builtin_amdgcn_sched_barrier(0);
    union { u32x2 d[2]; s8_t s; } u0, u1, u2, u3;
    u0.d[0] = t00; u0.d[1] = t01;
    u1.d[0] = t10; u1.d[1] = t11;
    u2.d[0] = t20; u2.d[1] = t21;
    u3.d[0] = t30; u3.d[1] = t31;
    oaccT[0] = __builtin_amdgcn_mfma_f32_16x16x32_bf16(u0.s, pb, oaccT[0], 0, 0, 0);
    oaccT[1] = __builtin_amdgcn_mfma_f32_16x16x32_bf16(u1.s, pb, oaccT[1], 0, 0, 0);
    oaccT[2] = __builtin_amdgcn_mfma_f32_16x16x32_bf16(u2.s, pb, oaccT[2], 0, 0, 0);
    oaccT[3] = __builtin_amdgcn_mfma_f32_16x16x32_bf16(u3.s, pb, oaccT[3], 0, 0, 0);
}

__global__ __launch_bounds__(256, 4) void attn_kernel(
    const float* __restrict__ qk, const float* __restrict__ v,
    const int* __restrict__ st_ws,
    __hip_bfloat16* __restrict__ o_ws, float* __restrict__ logits_ws)
{
    __shared__ char lds[LDS_TOT];
    float* nrm_s  = (float*)(lds + OFF_NRM);
    int*   tkx    = (int*)(lds + OFF_TKX);
    float* pinv_s = (float*)(lds + OFF_PINV);

    int tid = threadIdx.x;
    // XCD-contiguous swizzle: resident blocks share one batch's working set.
    int wg = blockIdx.x;
    int orig = ((wg & 7) << 10) + (wg >> 3);
    int c = orig & (CHUNKS - 1);
    int b = orig >> 9;
    int h = c >> 6;
    int sbase = b * (NH * S);
    int cprev = (c + CHUNKS - 1) & (CHUNKS - 1);

    int wv   = tid >> 6;
    int lane = tid & 63;
    int quad = lane >> 4;
    int cc   = lane & 15;
    int s_   = lane & 3;

    // ---- K gather FIRST (coalesced: 4 lanes/row) ----
    int rowA = wv * 32 + (lane >> 2);
    int rowB = rowA + 16;
    int chK  = (wv < 2) ? c : cprev;
    int tokKA = st_ws[sbase + chK * BS + (rowA & 63)];
    int tokKB = st_ws[sbase + chK * BS + (rowB & 63)];
    const float4* kpA = (const float4*)(qk + ((size_t)b * S + tokKA) * D);
    const float4* kpB = (const float4*)(qk + ((size_t)b * S + tokKB) * D);
    float4 kA4[4], kB4[4];
    #pragma unroll
    for (int n = 0; n < 4; ++n) { kA4[n] = kpA[n * 4 + s_]; kB4[n] = kpB[n * 4 + s_]; }

    // ---- V gather SECOND (coalesced; stays in flight under QK) ----
    int prA = wv * 32 + (lane >> 2);      // positions (kappa order)
    int prB = prA + 16;
    int ciA = ((prA & 3) << 4) | (prA >> 3);   // kappa^-1 within-chunk index
    int ciB = ((prB & 3) << 4) | (prB >> 3);
    int chVA = (prA & 4) ? cprev : c;
    int chVB = (prB & 4) ? cprev : c;
    int tokVA = st_ws[sbase + chVA * BS + ciA];
    int tokVB = st_ws[sbase + chVB * BS + ciB];
    const float4* vpA = (const float4*)(v + ((size_t)b * S + tokVA) * D);
    const float4* vpB = (const float4*)(v + ((size_t)b * S + tokVB) * D);
    float4 vA4[4], vB4[4];
    #pragma unroll
    for (int n = 0; n < 4; ++n) { vA4[n] = vpA[n * 4 + s_]; vB4[n] = vpB[n * 4 + s_]; }

    // ---- K process: norms + raw bf16 -> LDS ----
    {
        float ssA = 0.f, ssB = 0.f;
        #pragma unroll
        for (int n = 0; n < 4; ++n) {
            ssA += kA4[n].x*kA4[n].x + kA4[n].y*kA4[n].y
                 + kA4[n].z*kA4[n].z + kA4[n].w*kA4[n].w;
            ssB += kB4[n].x*kB4[n].x + kB4[n].y*kB4[n].y
                 + kB4[n].z*kB4[n].z + kB4[n].w*kB4[n].w;
        }
        ssA += __shfl_xor(ssA, 1, 64); ssA += __shfl_xor(ssA, 2, 64);
        ssB += __shfl_xor(ssB, 1, 64); ssB += __shfl_xor(ssB, 2, 64);
        if (s_ == 0) {
            nrm_s[rowA] = 1.0f / fmaxf(sqrtf(ssA), 1e-12f);
            nrm_s[rowB] = 1.0f / fmaxf(sqrtf(ssB), 1e-12f);
            tkx[rowA] = tokKA;
            tkx[rowB] = tokKB;
        }
        #pragma unroll
        for (int n = 0; n < 4; ++n) {
            *(uint2*)(lds + rowA * KSTRB + n * 32 + s_ * 8) =
                make_uint2(pack_trunc(kA4[n].x, kA4[n].y),
                           pack_trunc(kA4[n].z, kA4[n].w));
            *(uint2*)(lds + rowB * KSTRB + n * 32 + s_ * 8) =
                make_uint2(pack_trunc(kB4[n].x, kB4[n].y),
                           pack_trunc(kB4[n].z, kB4[n].w));
        }
    }
    BAR_LGKM();   // K/tkx/nrm visible; V loads legally still in flight

    // ---- dots: QK^T via bf16 MFMA (raw x raw) ----
    int qrow = wv * 16 + cc;
    f4_t acc[8];
    #pragma unroll
    for (int t = 0; t < 8; ++t) acc[t] = (f4_t){0.f,0.f,0.f,0.f};

    __builtin_amdgcn_s_setprio(1);
    #pragma unroll
    for (int kc = 0; kc < 2; ++kc) {
        int aoff = kc * 64 + quad * 16;
        s8_t av = *(const s8_t*)(lds + qrow * KSTRB + aoff);
        #pragma unroll
        for (int t = 0; t < 8; ++t) {
            s8_t bv = *(const s8_t*)(lds + (t * 16 + cc) * KSTRB + aoff);
            acc[t] = __builtin_amdgcn_mfma_f32_16x16x32_bf16(av, bv, acc[t], 0, 0, 0);
        }
    }
    __builtin_amdgcn_s_setprio(0);

    // ---- pack + write V (tr-subtiled; loads arrived under QK) ----
    {
        int kcA = prA >> 5, qA = (prA >> 3) & 3, rA = (prA >> 2) & 1, jA = prA & 3;
        int kcB = prB >> 5, qB = (prB >> 3) & 3, rB = (prB >> 2) & 1, jB = prB & 3;
        #pragma unroll
        for (int n = 0; n < 4; ++n) {
            *(uint2*)(lds + OFF_VT + (kcA * 8 + n * 2 + rA) * 544
                      + qA * 128 + jA * 32 + s_ * 8) =
                make_uint2(pack_trunc(vA4[n].x, vA4[n].y),
                           pack_trunc(vA4[n].z, vA4[n].w));
            *(uint2*)(lds + OFF_VT + (kcB * 8 + n * 2 + rB) * 544
                      + qB * 128 + jB * 32 + s_ * 8) =
                make_uint2(pack_trunc(vB4[n].x, vB4[n].y),
                           pack_trunc(vB4[n].z, vB4[n].w));
        }
    }

    // ---- scale (per-key inv-norm, log2 domain) + static self-mask ----
    float invsc[8];
    #pragma unroll
    for (int t = 0; t < 8; ++t)
        invsc[t] = nrm_s[t * 16 + cc] * 0.18033688f;   // 0.125 * log2(e) / |k|

    #pragma unroll
    for (int t = 0; t < 8; ++t) {
        #pragma unroll
        for (int g = 0; g < 4; ++g)
            acc[t][g] = acc[t][g] * invsc[t];
        if (t == wv) {          // scalar-uniform branch: self keys live here
            #pragma unroll
            for (int g = 0; g < 4; ++g)
                if (cc == quad * 4 + g) acc[t][g] = -3e5f;
        }
    }

    float mx[4];
    #pragma unroll
    for (int g = 0; g < 4; ++g) {
        float m = acc[0][g];
        #pragma unroll
        for (int t = 1; t < 8; ++t) m = fmaxf(m, acc[t][g]);
        mx[g] = m;
    }
    #pragma unroll
    for (int msk = 1; msk <= 8; msk <<= 1)
        #pragma unroll
        for (int g = 0; g < 4; ++g) mx[g] = fmaxf(mx[g], __shfl_xor(mx[g], msk, 64));

    float sm[4] = {0.f, 0.f, 0.f, 0.f};
    #pragma unroll
    for (int t = 0; t < 8; ++t)
        #pragma unroll
        for (int g = 0; g < 4; ++g) {
            float p = __builtin_amdgcn_exp2f(acc[t][g] - mx[g]);
            acc[t][g] = p;
            sm[g] += p;
        }
    #pragma unroll
    for (int msk = 1; msk <= 8; msk <<= 1)
        #pragma unroll
        for (int g = 0; g < 4; ++g) sm[g] += __shfl_xor(sm[g], msk, 64);

    int tqi[4];
    #pragma unroll
    for (int g = 0; g < 4; ++g) tqi[g] = tkx[wv * 16 + quad * 4 + g];

    if (cc == 0) {
        #pragma unroll
        for (int g = 0; g < 4; ++g) {
            int q = wv * 16 + quad * 4 + g;
            pinv_s[q] = 1.0f / sm[g];
            logits_ws[sbase + h * S + tqi[g]] =
                0.69314718f * (mx[g] + __log2f(sm[g]));
        }
    }

    // ---- P -> bf16 LDS in kappa order: 4 x b128/thread, overlaying K ----
    BAR_LGKM();   // all QK reads of K + V writes done; logits store in flight
    #pragma unroll
    for (int g = 0; g < 4; ++g) {
        int q = wv * 16 + quad * 4 + g;
        uint4 w;
        w.x = pack_trunc(acc[0][g], acc[1][g]);   // positions 8cc+0..7 = keys t*16+cc
        w.y = pack_trunc(acc[2][g], acc[3][g]);
        w.z = pack_trunc(acc[4][g], acc[5][g]);
        w.w = pack_trunc(acc[6][g], acc[7][g]);
        *(uint4*)(lds + q * PSTRB + cc * 16) = w;
    }

    // ---- PV as O^T = V^T * P via tr reads ----
    f4_t oaccT[4];
    #pragma unroll
    for (int n = 0; n < 4; ++n) oaccT[n] = (f4_t){0.f,0.f,0.f,0.f};

    unsigned vaddr = (unsigned)(unsigned long long)(lds + OFF_VT)
                   + (unsigned)lane * 8u;

    __builtin_amdgcn_s_setprio(1);
    pv_step<0>(lds, vaddr, wv, cc, quad, oaccT);
    pv_step<1>(lds, vaddr, wv, cc, quad, oaccT);
    pv_step<2>(lds, vaddr, wv, cc, quad, oaccT);
    pv_step<3>(lds, vaddr, wv, cc, quad, oaccT);
    __builtin_amdgcn_s_setprio(0);

    // ---- write O (bf16 trunc, scaled by deferred pinv): 4 x 8B stores ----
    {
        int q = wv * 16 + cc;
        int tok = tkx[q];                 // tkx region not overlaid by P
        float pq = pinv_s[q];
        __hip_bfloat16* op = o_ws + ((size_t)(sbase + h * S + tok)) * D + quad * 4;
        #pragma unroll
        for (int n = 0; n < 4; ++n) {
            uint2 pk2;
            pk2.x = pack_trunc(oaccT[n][0] * pq, oaccT[n][1] * pq);
            pk2.y = pack_trunc(oaccT[n][2] * pq, oaccT[n][3] * pq);
            *(uint2*)(op + n * 16) = pk2;
        }
    }
}

// ---------------------------------------------------------------------------
// Kernel 4: combine hash rounds with softmax(logits) weights. o_ws is bf16.
// ---------------------------------------------------------------------------
__global__ __launch_bounds__(256) void combine_kernel(
    const __hip_bfloat16* __restrict__ o_ws, const float* __restrict__ logits_ws,
    float* __restrict__ out)
{
    int gid = blockIdx.x * 256 + threadIdx.x;
    int token = gid >> 3;          // b*S + t
    int d8 = gid & 7;
    int b = token >> 12;
    int t = token & (S - 1);
    int base = b * (NH * S) + t;

    float l[8];
    #pragma unroll
    for (int hh = 0; hh < 8; ++hh) l[hh] = logits_ws[base + hh * S];
    float m = l[0];
    #pragma unroll
    for (int hh = 1; hh < 8; ++hh) m = fmaxf(m, l[hh]);
    float w[8]; float ssum = 0.f;
    #pragma unroll
    for (int hh = 0; hh < 8; ++hh) { w[hh] = __expf(l[hh] - m); ssum += w[hh]; }
    float inv = 1.0f / ssum;

    float accv[8] = {0,0,0,0,0,0,0,0};
    #pragma unroll
    for (int hh = 0; hh < 8; ++hh) {
        uint4 pk = *(const uint4*)(o_ws + (size_t)(base + hh * S) * D + d8 * 8);
        float wh = w[hh] * inv;
        unsigned int ws_[4] = {pk.x, pk.y, pk.z, pk.w};
        #pragma unroll
        for (int e = 0; e < 4; ++e) {
            float lo = __uint_as_float(ws_[e] << 16);
            float hi = __uint_as_float(ws_[e] & 0xffff0000u);
            accv[2*e]   += wh * lo;
            accv[2*e+1] += wh * hi;
        }
    }
    float4* op = (float4*)(out + (size_t)token * D + d8 * 8);
    op[0] = make_float4(accv[0], accv[1], accv[2], accv[3]);
    op[1] = make_float4(accv[4], accv[5], accv[6], accv[7]);
}

// ---------------------------------------------------------------------------
extern "C" void kernel_launch(void* const* d_in, const int* in_sizes, int n_in,
                              void* d_out, int out_size, void* d_ws, size_t ws_size,
                              hipStream_t stream) {
    const float* qk  = (const float*)d_in[0];
    const float* v   = (const float*)d_in[1];
    const float* rot = (const float*)d_in[2];

    float* out         = (float*)d_out;
    float* out_buckets = out + (size_t)B * S * D;

    int*   bucket_ws = (int*)d_ws;                              // 524288 ints
    int*   st_ws     = bucket_ws + (size_t)B * NH * S;          // 524288 ints
    float* logits_ws = (float*)(st_ws + (size_t)B * NH * S);    // 524288 f32
    __hip_bfloat16* o_ws = (__hip_bfloat16*)(logits_ws + (size_t)B * NH * S); // 64 MB
    unsigned char* flag_ws = (unsigned char*)(o_ws + (size_t)B * NH * S * D); // 512 KB

    hash_kernel<<<B * 32, 256, 0, stream>>>(qk, rot, out_buckets, bucket_ws,
                                            flag_ws);
    hash_fixup_kernel<<<(B * NH * S) / 2048, 256, 0, stream>>>(
        qk, rot, flag_ws, out_buckets, bucket_ws);
    sort_kernel<<<B * NH, 512, 0, stream>>>(bucket_ws, st_ws);
    attn_kernel<<<B * CHUNKS, 256, 0, stream>>>(qk, v, st_ws, o_ws, logits_ws);
    combine_kernel<<<(B * S * 8) / 256, 256, 0, stream>>>(o_ws, logits_ws, out);
}